// Round 30
// baseline (222.321 us; speedup 1.0000x reference)
//
#include <hip/hip_runtime.h>
#include <hip/hip_bf16.h>
#include <math.h>

#define N_NODES 5000
#define N_ELEMS 10
#define C_DIM   128
#define N_EDGE  100000
#define N_BES   8
#define RAD_H   64
#define NL      4
#define SH_DIM  16
#define TPW_ROWS 64

// scales
#define SC_SCALE 0.02795084971874737f    // 1/sqrt(128*10)
#define X_SCALE  0.08838834764831845f    // 1/sqrt(128)
#define R1_SCALE 0.3535533905932738f     // 1/sqrt(8)
#define R_SCALE  0.125f                  // 1/sqrt(64)
#define OUT_SCALE 0.004419417382415922f  // (1/sqrt(128))/20

typedef __attribute__((ext_vector_type(8))) short short8;
typedef __attribute__((ext_vector_type(4))) float f32x4;

__device__ __forceinline__ float silu(float v) { return v / (1.f + __expf(-v)); }
__device__ __forceinline__ unsigned short bf16bits(float v) {
    __hip_bfloat16 h = __float2bfloat16(v);
    return *(unsigned short*)&h;
}
__device__ __forceinline__ float bf16val(unsigned short b) {
    unsigned int u = ((unsigned int)b) << 16;
    return __uint_as_float(u);
}
__device__ __forceinline__ unsigned int packbf2(float lo, float hi) {
    return (unsigned int)bf16bits(lo) | ((unsigned int)bf16bits(hi) << 16);
}

// ---------------- node kernel: sc + x ----------------
__global__ __launch_bounds__(128) void node_kernel(
    const float* __restrict__ node_attrs, const float* __restrict__ node_feats,
    const float* __restrict__ w_skip, const float* __restrict__ w_up,
    float* __restrict__ x, float* __restrict__ sc_out)
{
    int n = blockIdx.x, t = threadIdx.x;
    __shared__ float f[C_DIM];
    __shared__ float at[N_ELEMS];
    f[t] = node_feats[(size_t)n * C_DIM + t];
    if (t < N_ELEMS) at[t] = node_attrs[(size_t)n * N_ELEMS + t];
    __syncthreads();

    float acc = 0.f;
    for (int a = 0; a < N_ELEMS; ++a) {
        float av = at[a];
        if (av != 0.f) {
            const float* wp = w_skip + a * C_DIM + t;
            float s2 = 0.f;
            #pragma unroll 8
            for (int c = 0; c < C_DIM; ++c) s2 += f[c] * wp[(size_t)c * (N_ELEMS * C_DIM)];
            acc += av * s2;
        }
    }
    sc_out[(size_t)n * C_DIM + t] = acc * SC_SCALE;

    float xa = 0.f;
    #pragma unroll 8
    for (int k = 0; k < C_DIM; ++k) xa += f[k] * w_up[k * C_DIM + t];
    x[(size_t)n * C_DIM + t] = xa * X_SCALE;
}

// ---------------- radial MLP v5: MFMA layers 2+3, h3 written bf16, perm order ----------------
__global__ __launch_bounds__(256, 2) void radial_mfma_kernel(
    const float* __restrict__ edge_feats, const int* __restrict__ pos_of,
    const float* __restrict__ w1, const float* __restrict__ w2, const float* __restrict__ w3,
    unsigned short* __restrict__ h3out)
{
    __shared__ unsigned short As[64 * 72];
    __shared__ unsigned short w2t[64 * 72];
    __shared__ unsigned short w3t[64 * 72];
    int t = threadIdx.x;
    int lane = t & 63, wid = t >> 6;

    for (int idx = t; idx < RAD_H * RAD_H; idx += 256) {
        int k = idx >> 6, n = idx & 63;
        w2t[n * 72 + k] = bf16bits(w2[k * RAD_H + n] * R_SCALE);
        w3t[n * 72 + k] = bf16bits(w3[k * RAD_H + n] * R_SCALE);
    }
    __syncthreads();

    short8 b2[2][4], b3[2][4];
    #pragma unroll
    for (int s = 0; s < 2; ++s)
        #pragma unroll
        for (int f = 0; f < 4; ++f) {
            b2[s][f] = *(const short8*)&w2t[(f * 16 + (lane & 15)) * 72 + s * 32 + (lane >> 4) * 8];
            b3[s][f] = *(const short8*)&w3t[(f * 16 + (lane & 15)) * 72 + s * 32 + (lane >> 4) * 8];
        }

    float w1r[N_BES];
    #pragma unroll
    for (int k = 0; k < N_BES; ++k) w1r[k] = w1[k * RAD_H + lane] * R1_SCALE;

    const int ntiles = (N_EDGE + 63) >> 6;
    for (int tile = blockIdx.x; tile < ntiles; tile += gridDim.x) {
        int i0 = tile << 6;
        int ebase = __builtin_amdgcn_readfirstlane(i0 + wid * 16);

        #pragma unroll 4
        for (int ee = 0; ee < 16; ++ee) {
            int e = min(ebase + ee, N_EDGE - 1);
            const float* ef = edge_feats + (size_t)e * N_BES;
            float a = 0.f;
            #pragma unroll
            for (int k = 0; k < N_BES; ++k) a += ef[k] * w1r[k];
            As[(wid * 16 + ee) * 72 + lane] = bf16bits(silu(a));
        }
        __builtin_amdgcn_wave_barrier();

        {
            short8 a0 = *(const short8*)&As[(wid * 16 + (lane & 15)) * 72 + 0 * 32 + (lane >> 4) * 8];
            short8 a1 = *(const short8*)&As[(wid * 16 + (lane & 15)) * 72 + 1 * 32 + (lane >> 4) * 8];
            f32x4 acc[4] = {};
            #pragma unroll
            for (int f = 0; f < 4; ++f) {
                acc[f] = __builtin_amdgcn_mfma_f32_16x16x32_bf16(a0, b2[0][f], acc[f], 0, 0, 0);
                acc[f] = __builtin_amdgcn_mfma_f32_16x16x32_bf16(a1, b2[1][f], acc[f], 0, 0, 0);
            }
            __builtin_amdgcn_wave_barrier();
            #pragma unroll
            for (int f = 0; f < 4; ++f)
                #pragma unroll
                for (int r = 0; r < 4; ++r)
                    As[(wid * 16 + (lane >> 4) * 4 + r) * 72 + f * 16 + (lane & 15)] =
                        bf16bits(silu(acc[f][r]));
        }
        __builtin_amdgcn_wave_barrier();

        {
            short8 a0 = *(const short8*)&As[(wid * 16 + (lane & 15)) * 72 + 0 * 32 + (lane >> 4) * 8];
            short8 a1 = *(const short8*)&As[(wid * 16 + (lane & 15)) * 72 + 1 * 32 + (lane >> 4) * 8];
            f32x4 acc[4] = {};
            #pragma unroll
            for (int f = 0; f < 4; ++f) {
                acc[f] = __builtin_amdgcn_mfma_f32_16x16x32_bf16(a0, b3[0][f], acc[f], 0, 0, 0);
                acc[f] = __builtin_amdgcn_mfma_f32_16x16x32_bf16(a1, b3[1][f], acc[f], 0, 0, 0);
            }
            #pragma unroll
            for (int r = 0; r < 4; ++r) {
                int e = i0 + wid * 16 + (lane >> 4) * 4 + r;
                if (e < N_EDGE) {
                    int row = pos_of[e];             // perm-ordered destination
                    unsigned short* dst = h3out + (size_t)row * RAD_H + (lane & 15);
                    #pragma unroll
                    for (int f = 0; f < 4; ++f)
                        dst[f * 16] = bf16bits(silu(acc[f][r]));
                }
            }
        }
        __builtin_amdgcn_wave_barrier();
    }
}

// ---------------- CSR build ----------------
__global__ void hist_kernel(const int* __restrict__ recv, int* __restrict__ deg)
{
    int e = blockIdx.x * 256 + threadIdx.x;
    if (e < N_EDGE) atomicAdd(&deg[recv[e]], 1);
}

__global__ __launch_bounds__(256) void scan_kernel(const int* __restrict__ deg, int* __restrict__ offs)
{
    __shared__ int sums[256];
    int t = threadIdx.x;
    int base = t * 20;
    int loc[20]; int s = 0;
    #pragma unroll
    for (int i = 0; i < 20; ++i) { int idx = base + i; int v = (idx < N_NODES) ? deg[idx] : 0; loc[i] = s; s += v; }
    sums[t] = s; __syncthreads();
    for (int off = 1; off < 256; off <<= 1) {
        int v = (t >= off) ? sums[t - off] : 0;
        __syncthreads();
        sums[t] += v;
        __syncthreads();
    }
    int ex = (t == 0) ? 0 : sums[t - 1];
    #pragma unroll
    for (int i = 0; i < 20; ++i) { int idx = base + i; if (idx < N_NODES) offs[idx] = ex + loc[i]; }
    if (t == 255) offs[N_NODES] = sums[255];
}

// scatter also records pos_of[e] = CSR index (inverse perm)
__global__ void scatter_kernel(const int* __restrict__ recv, const int* __restrict__ offs,
                               int* __restrict__ cursor, int* __restrict__ perm,
                               int* __restrict__ pos_of)
{
    int e = blockIdx.x * 256 + threadIdx.x;
    if (e < N_EDGE) {
        int r = recv[e];
        int pos = atomicAdd(&cursor[r], 1);
        int idx = offs[r] + pos;
        perm[idx] = e;
        pos_of[e] = idx;
    }
}

// ---------------- reorder: sid_arr[idx]=sender[perm[idx]], ea_perm[idx]=edge_attrs[perm[idx]] ----------------
__global__ void reorder_kernel(const int* __restrict__ perm, const int* __restrict__ sender,
                               const float* __restrict__ edge_attrs,
                               int* __restrict__ sid_arr, float4* __restrict__ ea_perm4)
{
    int idx = blockIdx.x * 256 + threadIdx.x;
    if (idx < N_EDGE) {
        int e = perm[idx];
        sid_arr[idx] = sender[e];
        const float4* src = (const float4*)(edge_attrs + (size_t)e * SH_DIM);
        float4* dst = ea_perm4 + (size_t)idx * 4;
        dst[0] = src[0]; dst[1] = src[1]; dst[2] = src[2]; dst[3] = src[3];
    }
}

// ---------------- tpw GEMM via MFMA: A-fragments DIRECT FROM GLOBAL (bf16 h3) ----------------
__global__ __launch_bounds__(256, 4) void tpw_gemm_kernel(
    const unsigned short* __restrict__ h3, const float* __restrict__ w4,
    __hip_bfloat16* __restrict__ tpw)
{
    __shared__ unsigned short uni[64 * 136];  // epi buffer only (17.4 KB)
    __shared__ unsigned short Bp[128 * 72];   // [n][k] pad 8 (18.4 KB)
    int l = blockIdx.y, t = threadIdx.x;
    int lane = t & 63, wid = t >> 6;

    for (int idx = t; idx < RAD_H * C_DIM; idx += 256) {
        int k = idx >> 7, n = idx & 127;
        Bp[n * 72 + k] = bf16bits(w4[k * (NL * C_DIM) + l * C_DIM + n] * R_SCALE);
    }
    __syncthreads();

    short8 bfr[2][8];
    #pragma unroll
    for (int s = 0; s < 2; ++s)
        #pragma unroll
        for (int f = 0; f < 8; ++f)
            bfr[s][f] = *(const short8*)&Bp[(f * 16 + (lane & 15)) * 72 + s * 32 + (lane >> 4) * 8];

    const int ntiles = (N_EDGE + TPW_ROWS - 1) / TPW_ROWS;   // 1563
    short8 a_cur[2];
    {
        int arow = min((int)blockIdx.x * TPW_ROWS + wid * 16 + (lane & 15), N_EDGE - 1);
        a_cur[0] = *(const short8*)&h3[(size_t)arow * RAD_H + 0 * 32 + (lane >> 4) * 8];
        a_cur[1] = *(const short8*)&h3[(size_t)arow * RAD_H + 1 * 32 + (lane >> 4) * 8];
    }
    for (int tile = blockIdx.x; tile < ntiles; tile += gridDim.x) {
        int i0 = tile * TPW_ROWS;
        short8 a_nxt[2];
        int ntile2 = tile + gridDim.x;
        if (ntile2 < ntiles) {
            int arow = min(ntile2 * TPW_ROWS + wid * 16 + (lane & 15), N_EDGE - 1);
            a_nxt[0] = *(const short8*)&h3[(size_t)arow * RAD_H + 0 * 32 + (lane >> 4) * 8];
            a_nxt[1] = *(const short8*)&h3[(size_t)arow * RAD_H + 1 * 32 + (lane >> 4) * 8];
        }

        f32x4 acc[8] = {};
        #pragma unroll
        for (int s = 0; s < 2; ++s)
            #pragma unroll
            for (int f = 0; f < 8; ++f)
                acc[f] = __builtin_amdgcn_mfma_f32_16x16x32_bf16(a_cur[s], bfr[s][f], acc[f], 0, 0, 0);

        __syncthreads();    // prev copy-out done before epi overwrite
        #pragma unroll
        for (int f = 0; f < 8; ++f)
            #pragma unroll
            for (int r = 0; r < 4; ++r)
                uni[(wid * 16 + (lane >> 4) * 4 + r) * 136 + f * 16 + (lane & 15)] = bf16bits(acc[f][r]);
        __syncthreads();    // epi ready

        {
            int row = t >> 2, q = t & 3;
            if (i0 + row < N_EDGE) {
                unsigned short* dst = (unsigned short*)tpw + (size_t)(i0 + row) * (NL * C_DIM) + l * C_DIM + q * 32;
                #pragma unroll
                for (int v = 0; v < 4; ++v)
                    *(short8*)(dst + v * 8) = *(const short8*)&uni[row * 136 + q * 32 + v * 8];
            }
        }
        a_cur[0] = a_nxt[0];
        a_cur[1] = a_nxt[1];
    }
}

// ---------------- stream gather v6: msg written as BF16 (feeds out_mfma direct) ----------------
__global__ __launch_bounds__(256, 4) void stream_gather_kernel(
    const int* __restrict__ offs, const int* __restrict__ sid_arr,
    const float* __restrict__ x, const float* __restrict__ ea_perm,
    const __hip_bfloat16* __restrict__ tpw, unsigned short* __restrict__ msgbf)
{
    __shared__ float eas[128 * SH_DIM];   // 8 KB
    __shared__ int   sids[128];
    int n = blockIdx.x, t = threadIdx.x;
    int cq = t & 63, l = t >> 6;
    int c0 = cq * 2;
    float acc[7][2] = {};
    int nm = 2 * l + 1;
    int start = offs[n], end = offs[n + 1];

    for (int cs = start; cs < end; cs += 128) {
        int clen = min(128, end - cs);
        {
            const float4* src = (const float4*)(ea_perm + (size_t)cs * SH_DIM);
            float4* dst = (float4*)eas;
            for (int i = t; i < clen * 4; i += 256) dst[i] = src[i];
            for (int i = t; i < clen; i += 256) sids[i] = sid_arr[cs + i];
        }
        __syncthreads();

        for (int base = 0; base < clen; base += 8) {
            int idxb[8], sidb[8];
            #pragma unroll
            for (int j = 0; j < 8; ++j) idxb[j] = min(base + j, clen - 1);
            #pragma unroll
            for (int j = 0; j < 8; ++j) sidb[j] = sids[idxb[j]];

            unsigned int tpb[8];
            float2 xv[8];
            #pragma unroll
            for (int j = 0; j < 8; ++j)
                tpb[j] = *(const unsigned int*)((const unsigned short*)tpw
                          + (size_t)(cs + idxb[j]) * (NL * C_DIM) + l * C_DIM + c0);
            #pragma unroll
            for (int j = 0; j < 8; ++j)
                xv[j] = *(const float2*)(x + (size_t)sidb[j] * C_DIM + c0);
            asm volatile("" : "+v"(tpb[0]), "+v"(tpb[1]), "+v"(tpb[2]), "+v"(tpb[3]),
                              "+v"(tpb[4]), "+v"(tpb[5]), "+v"(tpb[6]), "+v"(tpb[7]),
                              "+v"(xv[0].x), "+v"(xv[0].y), "+v"(xv[1].x), "+v"(xv[1].y),
                              "+v"(xv[2].x), "+v"(xv[2].y), "+v"(xv[3].x), "+v"(xv[3].y),
                              "+v"(xv[4].x), "+v"(xv[4].y), "+v"(xv[5].x), "+v"(xv[5].y),
                              "+v"(xv[6].x), "+v"(xv[6].y), "+v"(xv[7].x), "+v"(xv[7].y));

            #pragma unroll
            for (int j = 0; j < 8; ++j) {
                unsigned int lo = (tpb[j] & 0xFFFFu) << 16;
                unsigned int hi = tpb[j] & 0xFFFF0000u;
                float tp0 = __uint_as_float(lo);
                float tp1 = __uint_as_float(hi);
                bool valid = (base + j < clen);
                float xt0 = valid ? tp0 * xv[j].x : 0.f;
                float xt1 = valid ? tp1 * xv[j].y : 0.f;
                const float* ear = eas + idxb[j] * SH_DIM + l * l;
                #pragma unroll
                for (int m = 0; m < 7; ++m)
                    if (m < nm) { acc[m][0] += ear[m] * xt0; acc[m][1] += ear[m] * xt1; }
            }
        }
        __syncthreads();
    }
    unsigned short* mout = msgbf + (size_t)n * (SH_DIM * C_DIM) + (size_t)(l * l) * C_DIM + c0;
    #pragma unroll
    for (int m = 0; m < 7; ++m)
        if (m < nm) *(unsigned int*)(mout + (size_t)m * C_DIM) = packbf2(acc[m][0], acc[m][1]);
}

// ---------------- fallback fused gather (h3 bf16, perm-ordered; msg bf16 out) ----------------
__global__ __launch_bounds__(512, 4) void fused_gather_kernel(
    const int* __restrict__ perm, const int* __restrict__ offs,
    const int* __restrict__ sender, const float* __restrict__ x,
    const float* __restrict__ edge_attrs, const unsigned short* __restrict__ h3,
    const float* __restrict__ w4, unsigned short* __restrict__ msgbf)
{
    int n = blockIdx.x, t = threadIdx.x;
    int c = t & 127, l = t >> 7;
    float wc[RAD_H];
    #pragma unroll
    for (int k = 0; k < RAD_H; ++k)
        wc[k] = w4[k * (NL * C_DIM) + l * C_DIM + c];

    float acc[7] = {0.f, 0.f, 0.f, 0.f, 0.f, 0.f, 0.f};
    int nm = 2 * l + 1;
    int start = offs[n], end = offs[n + 1];
    if (start < end) {
        int e = __builtin_amdgcn_readfirstlane(perm[start]);
        int s = __builtin_amdgcn_readfirstlane(sender[e]);
        for (int idx = start; idx < end; ++idx) {
            #pragma unroll
            for (int k = 0; k < RAD_H; k += 8)
                asm volatile("" : "+v"(wc[k]), "+v"(wc[k+1]), "+v"(wc[k+2]), "+v"(wc[k+3]),
                                  "+v"(wc[k+4]), "+v"(wc[k+5]), "+v"(wc[k+6]), "+v"(wc[k+7]));
            int e_cur = e, s_cur = s;
            if (idx + 1 < end) {
                e = __builtin_amdgcn_readfirstlane(perm[idx + 1]);
                s = __builtin_amdgcn_readfirstlane(sender[e]);
            }
            const unsigned short* h3r = h3 + (size_t)idx * RAD_H;   // perm-ordered bf16
            float xv = x[(size_t)s_cur * C_DIM + c];
            float tp0 = 0.f, tp1 = 0.f, tp2 = 0.f, tp3 = 0.f;
            #pragma unroll
            for (int q = 0; q < RAD_H / 4; ++q) {
                tp0 += bf16val(h3r[4 * q + 0]) * wc[4 * q + 0];
                tp1 += bf16val(h3r[4 * q + 1]) * wc[4 * q + 1];
                tp2 += bf16val(h3r[4 * q + 2]) * wc[4 * q + 2];
                tp3 += bf16val(h3r[4 * q + 3]) * wc[4 * q + 3];
            }
            float tp = (tp0 + tp1) + (tp2 + tp3);
            float xt = xv * (tp * R_SCALE);
            const float* ear = edge_attrs + (size_t)e_cur * SH_DIM + l * l;
            #pragma unroll
            for (int j = 0; j < 7; ++j)
                if (j < nm) acc[j] += ear[j] * xt;
        }
    }
    unsigned short* mout = msgbf + (size_t)n * (SH_DIM * C_DIM) + (size_t)(l * l) * C_DIM + c;
    #pragma unroll
    for (int j = 0; j < 7; ++j)
        if (j < nm) mout[(size_t)j * C_DIM] = bf16bits(acc[j]);
}

// ---------------- out transform via MFMA v2: A DIRECT FROM GLOBAL (bf16 msg) ----------------
// Round-29 change: msg stored bf16 -> no A-staging (round-29-proven direct
// fragment loads), LDS 69.6 -> 34.8 KB, (256,4). Writes f32 to d_out (no
// in-place hazard: msg lives in workspace).
__global__ __launch_bounds__(256, 4) void out_mfma_kernel(
    const unsigned short* __restrict__ msgbf, float* __restrict__ out,
    const float* __restrict__ w_out)
{
    __shared__ unsigned short Bp[128 * 136];   // 34.8 KB
    int l = blockIdx.y, t = threadIdx.x;
    int lane = t & 63, wid = t >> 6;
    const int cnt = 2 * l + 1, ms = l * l;
    const int M = N_NODES * cnt;
    const int ntile = (M + 63) >> 6;
    if (blockIdx.x >= ntile) return;

    for (int idx = t; idx < C_DIM * C_DIM; idx += 256) {
        int k = idx >> 7, n = idx & 127;
        Bp[n * 136 + k] = bf16bits(w_out[((size_t)l * C_DIM + k) * C_DIM + n] * OUT_SCALE);
    }
    __syncthreads();

    for (int tile = blockIdx.x; tile < ntile; tile += gridDim.x) {
        int i0 = tile << 6;
        // A-fragment rows direct from global bf16 msg
        int g_a = min(i0 + wid * 16 + (lane & 15), M - 1);
        int node_a = g_a / cnt, mm_a = ms + (g_a - node_a * cnt);
        const unsigned short* arow = msgbf + ((size_t)node_a * SH_DIM + mm_a) * C_DIM;

        f32x4 acc[8] = {};
        #pragma unroll
        for (int ks = 0; ks < 4; ++ks) {
            short8 a = *(const short8*)&arow[ks * 32 + (lane >> 4) * 8];
            #pragma unroll
            for (int f = 0; f < 8; ++f) {
                short8 b = *(const short8*)&Bp[(f * 16 + (lane & 15)) * 136 + ks * 32 + (lane >> 4) * 8];
                acc[f] = __builtin_amdgcn_mfma_f32_16x16x32_bf16(a, b, acc[f], 0, 0, 0);
            }
        }

        #pragma unroll
        for (int r = 0; r < 4; ++r) {
            int g = i0 + wid * 16 + (lane >> 4) * 4 + r;
            if (g < M) {
                int node = g / cnt, mm = ms + (g - node * cnt);
                float* dst = out + ((size_t)node * SH_DIM + mm) * C_DIM + (lane & 15);
                #pragma unroll
                for (int f = 0; f < 8; ++f)
                    dst[f * 16] = acc[f][r];
            }
        }
    }
}

extern "C" void kernel_launch(void* const* d_in, const int* in_sizes, int n_in,
                              void* d_out, int out_size, void* d_ws, size_t ws_size,
                              hipStream_t stream)
{
    const float* node_attrs = (const float*)d_in[0];
    const float* node_feats = (const float*)d_in[1];
    const float* edge_attrs = (const float*)d_in[2];
    const float* edge_feats = (const float*)d_in[3];
    const int*   edge_index = (const int*)d_in[4];
    const float* w_up   = (const float*)d_in[5];
    const float* w_rad1 = (const float*)d_in[6];
    const float* w_rad2 = (const float*)d_in[7];
    const float* w_rad3 = (const float*)d_in[8];
    const float* w_rad4 = (const float*)d_in[9];
    const float* w_skip = (const float*)d_in[10];
    const float* w_out  = (const float*)d_in[11];
    const int* sender = edge_index;
    const int* recv   = edge_index + N_EDGE;

    float* out = (float*)d_out;
    float* sc  = out + (size_t)N_NODES * SH_DIM * C_DIM;

    // workspace layout (~147 MB; ws >= 233.4 MB proven)
    float* x   = (float*)d_ws;
    unsigned short* h3 = (unsigned short*)(x + (size_t)N_NODES * C_DIM);  // bf16, perm-ordered
    int* deg    = (int*)(h3 + (size_t)N_EDGE * RAD_H);
    int* cursor = deg + 5120;
    int* offs   = cursor + 5120;
    int* perm   = offs + 5124;
    int* pos_of = perm + N_EDGE;
    __hip_bfloat16* tpw = (__hip_bfloat16*)(pos_of + N_EDGE);
    int* sid_arr = (int*)(tpw + (size_t)N_EDGE * NL * C_DIM);
    float* ea_perm = (float*)(sid_arr + N_EDGE);
    unsigned short* msgbf = (unsigned short*)(ea_perm + (size_t)N_EDGE * SH_DIM);  // 20.5 MB
    size_t need = (size_t)((char*)(msgbf + (size_t)N_NODES * SH_DIM * C_DIM) - (char*)d_ws);
    int mode = (ws_size >= need) ? 1 : 0;

    hipMemsetAsync(deg, 0, 2 * 5120 * sizeof(int), stream);

    node_kernel<<<N_NODES, 128, 0, stream>>>(node_attrs, node_feats, w_skip, w_up, x, sc);

    // CSR build BEFORE radial (radial writes h3 in perm order via pos_of)
    hist_kernel<<<(N_EDGE + 255) / 256, 256, 0, stream>>>(recv, deg);
    scan_kernel<<<1, 256, 0, stream>>>(deg, offs);
    scatter_kernel<<<(N_EDGE + 255) / 256, 256, 0, stream>>>(recv, offs, cursor, perm, pos_of);

    radial_mfma_kernel<<<391, 256, 0, stream>>>(edge_feats, pos_of, w_rad1, w_rad2, w_rad3, h3);

    if (mode == 1) {
        reorder_kernel<<<(N_EDGE + 255) / 256, 256, 0, stream>>>(perm, sender, edge_attrs, sid_arr, (float4*)ea_perm);
        tpw_gemm_kernel<<<dim3(391, 4), 256, 0, stream>>>(h3, w_rad4, tpw);
        stream_gather_kernel<<<N_NODES, 256, 0, stream>>>(offs, sid_arr, x, ea_perm, tpw, msgbf);
        out_mfma_kernel<<<dim3(547, 4), 256, 0, stream>>>(msgbf, out, w_out);
    } else {
        // fallback needs only up to ea_perm-start; msgbf placed at tpw slot
        unsigned short* msgbf_fb = (unsigned short*)tpw;
        fused_gather_kernel<<<N_NODES, 512, 0, stream>>>(perm, offs, sender, x, edge_attrs, h3, w_rad4, msgbf_fb);
        out_mfma_kernel<<<dim3(547, 4), 256, 0, stream>>>(msgbf_fb, out, w_out);
    }
}

// Round 31
// 190.369 us; speedup vs baseline: 1.1678x; 1.1678x over previous
//
#include <hip/hip_runtime.h>
#include <hip/hip_bf16.h>
#include <math.h>

#define N_NODES 5000
#define N_ELEMS 10
#define C_DIM   128
#define N_EDGE  100000
#define N_BES   8
#define RAD_H   64
#define NL      4
#define SH_DIM  16
#define TPW_ROWS 64

// scales
#define SC_SCALE 0.02795084971874737f    // 1/sqrt(128*10)
#define X_SCALE  0.08838834764831845f    // 1/sqrt(128)
#define R1_SCALE 0.3535533905932738f     // 1/sqrt(8)
#define R_SCALE  0.125f                  // 1/sqrt(64)
#define OUT_SCALE 0.004419417382415922f  // (1/sqrt(128))/20

typedef __attribute__((ext_vector_type(8))) short short8;
typedef __attribute__((ext_vector_type(4))) float f32x4;

__device__ __forceinline__ float silu(float v) { return v / (1.f + __expf(-v)); }
__device__ __forceinline__ unsigned short bf16bits(float v) {
    __hip_bfloat16 h = __float2bfloat16(v);
    return *(unsigned short*)&h;
}
__device__ __forceinline__ float bf16val(unsigned short b) {
    unsigned int u = ((unsigned int)b) << 16;
    return __uint_as_float(u);
}
__device__ __forceinline__ unsigned int packbf2(float lo, float hi) {
    return (unsigned int)bf16bits(lo) | ((unsigned int)bf16bits(hi) << 16);
}

// ---------------- node kernel: sc + x ----------------
__global__ __launch_bounds__(128) void node_kernel(
    const float* __restrict__ node_attrs, const float* __restrict__ node_feats,
    const float* __restrict__ w_skip, const float* __restrict__ w_up,
    float* __restrict__ x, float* __restrict__ sc_out)
{
    int n = blockIdx.x, t = threadIdx.x;
    __shared__ float f[C_DIM];
    __shared__ float at[N_ELEMS];
    f[t] = node_feats[(size_t)n * C_DIM + t];
    if (t < N_ELEMS) at[t] = node_attrs[(size_t)n * N_ELEMS + t];
    __syncthreads();

    float acc = 0.f;
    for (int a = 0; a < N_ELEMS; ++a) {
        float av = at[a];
        if (av != 0.f) {
            const float* wp = w_skip + a * C_DIM + t;
            float s2 = 0.f;
            #pragma unroll 8
            for (int c = 0; c < C_DIM; ++c) s2 += f[c] * wp[(size_t)c * (N_ELEMS * C_DIM)];
            acc += av * s2;
        }
    }
    sc_out[(size_t)n * C_DIM + t] = acc * SC_SCALE;

    float xa = 0.f;
    #pragma unroll 8
    for (int k = 0; k < C_DIM; ++k) xa += f[k] * w_up[k * C_DIM + t];
    x[(size_t)n * C_DIM + t] = xa * X_SCALE;
}

// ---------------- radial MLP v5: MFMA layers 2+3, h3 written bf16, perm order ----------------
__global__ __launch_bounds__(256, 2) void radial_mfma_kernel(
    const float* __restrict__ edge_feats, const int* __restrict__ pos_of,
    const float* __restrict__ w1, const float* __restrict__ w2, const float* __restrict__ w3,
    unsigned short* __restrict__ h3out)
{
    __shared__ unsigned short As[64 * 72];
    __shared__ unsigned short w2t[64 * 72];
    __shared__ unsigned short w3t[64 * 72];
    int t = threadIdx.x;
    int lane = t & 63, wid = t >> 6;

    for (int idx = t; idx < RAD_H * RAD_H; idx += 256) {
        int k = idx >> 6, n = idx & 63;
        w2t[n * 72 + k] = bf16bits(w2[k * RAD_H + n] * R_SCALE);
        w3t[n * 72 + k] = bf16bits(w3[k * RAD_H + n] * R_SCALE);
    }
    __syncthreads();

    short8 b2[2][4], b3[2][4];
    #pragma unroll
    for (int s = 0; s < 2; ++s)
        #pragma unroll
        for (int f = 0; f < 4; ++f) {
            b2[s][f] = *(const short8*)&w2t[(f * 16 + (lane & 15)) * 72 + s * 32 + (lane >> 4) * 8];
            b3[s][f] = *(const short8*)&w3t[(f * 16 + (lane & 15)) * 72 + s * 32 + (lane >> 4) * 8];
        }

    float w1r[N_BES];
    #pragma unroll
    for (int k = 0; k < N_BES; ++k) w1r[k] = w1[k * RAD_H + lane] * R1_SCALE;

    const int ntiles = (N_EDGE + 63) >> 6;
    for (int tile = blockIdx.x; tile < ntiles; tile += gridDim.x) {
        int i0 = tile << 6;
        int ebase = __builtin_amdgcn_readfirstlane(i0 + wid * 16);

        #pragma unroll 4
        for (int ee = 0; ee < 16; ++ee) {
            int e = min(ebase + ee, N_EDGE - 1);
            const float* ef = edge_feats + (size_t)e * N_BES;
            float a = 0.f;
            #pragma unroll
            for (int k = 0; k < N_BES; ++k) a += ef[k] * w1r[k];
            As[(wid * 16 + ee) * 72 + lane] = bf16bits(silu(a));
        }
        __builtin_amdgcn_wave_barrier();

        {
            short8 a0 = *(const short8*)&As[(wid * 16 + (lane & 15)) * 72 + 0 * 32 + (lane >> 4) * 8];
            short8 a1 = *(const short8*)&As[(wid * 16 + (lane & 15)) * 72 + 1 * 32 + (lane >> 4) * 8];
            f32x4 acc[4] = {};
            #pragma unroll
            for (int f = 0; f < 4; ++f) {
                acc[f] = __builtin_amdgcn_mfma_f32_16x16x32_bf16(a0, b2[0][f], acc[f], 0, 0, 0);
                acc[f] = __builtin_amdgcn_mfma_f32_16x16x32_bf16(a1, b2[1][f], acc[f], 0, 0, 0);
            }
            __builtin_amdgcn_wave_barrier();
            #pragma unroll
            for (int f = 0; f < 4; ++f)
                #pragma unroll
                for (int r = 0; r < 4; ++r)
                    As[(wid * 16 + (lane >> 4) * 4 + r) * 72 + f * 16 + (lane & 15)] =
                        bf16bits(silu(acc[f][r]));
        }
        __builtin_amdgcn_wave_barrier();

        {
            short8 a0 = *(const short8*)&As[(wid * 16 + (lane & 15)) * 72 + 0 * 32 + (lane >> 4) * 8];
            short8 a1 = *(const short8*)&As[(wid * 16 + (lane & 15)) * 72 + 1 * 32 + (lane >> 4) * 8];
            f32x4 acc[4] = {};
            #pragma unroll
            for (int f = 0; f < 4; ++f) {
                acc[f] = __builtin_amdgcn_mfma_f32_16x16x32_bf16(a0, b3[0][f], acc[f], 0, 0, 0);
                acc[f] = __builtin_amdgcn_mfma_f32_16x16x32_bf16(a1, b3[1][f], acc[f], 0, 0, 0);
            }
            #pragma unroll
            for (int r = 0; r < 4; ++r) {
                int e = i0 + wid * 16 + (lane >> 4) * 4 + r;
                if (e < N_EDGE) {
                    int row = pos_of[e];             // perm-ordered destination
                    unsigned short* dst = h3out + (size_t)row * RAD_H + (lane & 15);
                    #pragma unroll
                    for (int f = 0; f < 4; ++f)
                        dst[f * 16] = bf16bits(silu(acc[f][r]));
                }
            }
        }
        __builtin_amdgcn_wave_barrier();
    }
}

// ---------------- CSR build ----------------
__global__ void hist_kernel(const int* __restrict__ recv, int* __restrict__ deg)
{
    int e = blockIdx.x * 256 + threadIdx.x;
    if (e < N_EDGE) atomicAdd(&deg[recv[e]], 1);
}

__global__ __launch_bounds__(256) void scan_kernel(const int* __restrict__ deg, int* __restrict__ offs)
{
    __shared__ int sums[256];
    int t = threadIdx.x;
    int base = t * 20;
    int loc[20]; int s = 0;
    #pragma unroll
    for (int i = 0; i < 20; ++i) { int idx = base + i; int v = (idx < N_NODES) ? deg[idx] : 0; loc[i] = s; s += v; }
    sums[t] = s; __syncthreads();
    for (int off = 1; off < 256; off <<= 1) {
        int v = (t >= off) ? sums[t - off] : 0;
        __syncthreads();
        sums[t] += v;
        __syncthreads();
    }
    int ex = (t == 0) ? 0 : sums[t - 1];
    #pragma unroll
    for (int i = 0; i < 20; ++i) { int idx = base + i; if (idx < N_NODES) offs[idx] = ex + loc[i]; }
    if (t == 255) offs[N_NODES] = sums[255];
}

// scatter also records pos_of[e] = CSR index (inverse perm)
__global__ void scatter_kernel(const int* __restrict__ recv, const int* __restrict__ offs,
                               int* __restrict__ cursor, int* __restrict__ perm,
                               int* __restrict__ pos_of)
{
    int e = blockIdx.x * 256 + threadIdx.x;
    if (e < N_EDGE) {
        int r = recv[e];
        int pos = atomicAdd(&cursor[r], 1);
        int idx = offs[r] + pos;
        perm[idx] = e;
        pos_of[e] = idx;
    }
}

// ---------------- reorder: sid_arr[idx]=sender[perm[idx]], ea_perm[idx]=edge_attrs[perm[idx]] ----------------
__global__ void reorder_kernel(const int* __restrict__ perm, const int* __restrict__ sender,
                               const float* __restrict__ edge_attrs,
                               int* __restrict__ sid_arr, float4* __restrict__ ea_perm4)
{
    int idx = blockIdx.x * 256 + threadIdx.x;
    if (idx < N_EDGE) {
        int e = perm[idx];
        sid_arr[idx] = sender[e];
        const float4* src = (const float4*)(edge_attrs + (size_t)e * SH_DIM);
        float4* dst = ea_perm4 + (size_t)idx * 4;
        dst[0] = src[0]; dst[1] = src[1]; dst[2] = src[2]; dst[3] = src[3];
    }
}

// ---------------- tpw GEMM via MFMA: A-fragments DIRECT FROM GLOBAL (bf16 h3) ----------------
__global__ __launch_bounds__(256, 4) void tpw_gemm_kernel(
    const unsigned short* __restrict__ h3, const float* __restrict__ w4,
    __hip_bfloat16* __restrict__ tpw)
{
    __shared__ unsigned short uni[64 * 136];  // epi buffer only (17.4 KB)
    __shared__ unsigned short Bp[128 * 72];   // [n][k] pad 8 (18.4 KB)
    int l = blockIdx.y, t = threadIdx.x;
    int lane = t & 63, wid = t >> 6;

    for (int idx = t; idx < RAD_H * C_DIM; idx += 256) {
        int k = idx >> 7, n = idx & 127;
        Bp[n * 72 + k] = bf16bits(w4[k * (NL * C_DIM) + l * C_DIM + n] * R_SCALE);
    }
    __syncthreads();

    short8 bfr[2][8];
    #pragma unroll
    for (int s = 0; s < 2; ++s)
        #pragma unroll
        for (int f = 0; f < 8; ++f)
            bfr[s][f] = *(const short8*)&Bp[(f * 16 + (lane & 15)) * 72 + s * 32 + (lane >> 4) * 8];

    const int ntiles = (N_EDGE + TPW_ROWS - 1) / TPW_ROWS;   // 1563
    short8 a_cur[2];
    {
        int arow = min((int)blockIdx.x * TPW_ROWS + wid * 16 + (lane & 15), N_EDGE - 1);
        a_cur[0] = *(const short8*)&h3[(size_t)arow * RAD_H + 0 * 32 + (lane >> 4) * 8];
        a_cur[1] = *(const short8*)&h3[(size_t)arow * RAD_H + 1 * 32 + (lane >> 4) * 8];
    }
    for (int tile = blockIdx.x; tile < ntiles; tile += gridDim.x) {
        int i0 = tile * TPW_ROWS;
        short8 a_nxt[2];
        int ntile2 = tile + gridDim.x;
        if (ntile2 < ntiles) {
            int arow = min(ntile2 * TPW_ROWS + wid * 16 + (lane & 15), N_EDGE - 1);
            a_nxt[0] = *(const short8*)&h3[(size_t)arow * RAD_H + 0 * 32 + (lane >> 4) * 8];
            a_nxt[1] = *(const short8*)&h3[(size_t)arow * RAD_H + 1 * 32 + (lane >> 4) * 8];
        }

        f32x4 acc[8] = {};
        #pragma unroll
        for (int s = 0; s < 2; ++s)
            #pragma unroll
            for (int f = 0; f < 8; ++f)
                acc[f] = __builtin_amdgcn_mfma_f32_16x16x32_bf16(a_cur[s], bfr[s][f], acc[f], 0, 0, 0);

        __syncthreads();    // prev copy-out done before epi overwrite
        #pragma unroll
        for (int f = 0; f < 8; ++f)
            #pragma unroll
            for (int r = 0; r < 4; ++r)
                uni[(wid * 16 + (lane >> 4) * 4 + r) * 136 + f * 16 + (lane & 15)] = bf16bits(acc[f][r]);
        __syncthreads();    // epi ready

        {
            int row = t >> 2, q = t & 3;
            if (i0 + row < N_EDGE) {
                unsigned short* dst = (unsigned short*)tpw + (size_t)(i0 + row) * (NL * C_DIM) + l * C_DIM + q * 32;
                #pragma unroll
                for (int v = 0; v < 4; ++v)
                    *(short8*)(dst + v * 8) = *(const short8*)&uni[row * 136 + q * 32 + v * 8];
            }
        }
        a_cur[0] = a_nxt[0];
        a_cur[1] = a_nxt[1];
    }
}

// ---------------- stream gather v6: msg written as BF16 (feeds out_mfma) ----------------
__global__ __launch_bounds__(256, 4) void stream_gather_kernel(
    const int* __restrict__ offs, const int* __restrict__ sid_arr,
    const float* __restrict__ x, const float* __restrict__ ea_perm,
    const __hip_bfloat16* __restrict__ tpw, unsigned short* __restrict__ msgbf)
{
    __shared__ float eas[128 * SH_DIM];   // 8 KB
    __shared__ int   sids[128];
    int n = blockIdx.x, t = threadIdx.x;
    int cq = t & 63, l = t >> 6;
    int c0 = cq * 2;
    float acc[7][2] = {};
    int nm = 2 * l + 1;
    int start = offs[n], end = offs[n + 1];

    for (int cs = start; cs < end; cs += 128) {
        int clen = min(128, end - cs);
        {
            const float4* src = (const float4*)(ea_perm + (size_t)cs * SH_DIM);
            float4* dst = (float4*)eas;
            for (int i = t; i < clen * 4; i += 256) dst[i] = src[i];
            for (int i = t; i < clen; i += 256) sids[i] = sid_arr[cs + i];
        }
        __syncthreads();

        for (int base = 0; base < clen; base += 8) {
            int idxb[8], sidb[8];
            #pragma unroll
            for (int j = 0; j < 8; ++j) idxb[j] = min(base + j, clen - 1);
            #pragma unroll
            for (int j = 0; j < 8; ++j) sidb[j] = sids[idxb[j]];

            unsigned int tpb[8];
            float2 xv[8];
            #pragma unroll
            for (int j = 0; j < 8; ++j)
                tpb[j] = *(const unsigned int*)((const unsigned short*)tpw
                          + (size_t)(cs + idxb[j]) * (NL * C_DIM) + l * C_DIM + c0);
            #pragma unroll
            for (int j = 0; j < 8; ++j)
                xv[j] = *(const float2*)(x + (size_t)sidb[j] * C_DIM + c0);
            asm volatile("" : "+v"(tpb[0]), "+v"(tpb[1]), "+v"(tpb[2]), "+v"(tpb[3]),
                              "+v"(tpb[4]), "+v"(tpb[5]), "+v"(tpb[6]), "+v"(tpb[7]),
                              "+v"(xv[0].x), "+v"(xv[0].y), "+v"(xv[1].x), "+v"(xv[1].y),
                              "+v"(xv[2].x), "+v"(xv[2].y), "+v"(xv[3].x), "+v"(xv[3].y),
                              "+v"(xv[4].x), "+v"(xv[4].y), "+v"(xv[5].x), "+v"(xv[5].y),
                              "+v"(xv[6].x), "+v"(xv[6].y), "+v"(xv[7].x), "+v"(xv[7].y));

            #pragma unroll
            for (int j = 0; j < 8; ++j) {
                unsigned int lo = (tpb[j] & 0xFFFFu) << 16;
                unsigned int hi = tpb[j] & 0xFFFF0000u;
                float tp0 = __uint_as_float(lo);
                float tp1 = __uint_as_float(hi);
                bool valid = (base + j < clen);
                float xt0 = valid ? tp0 * xv[j].x : 0.f;
                float xt1 = valid ? tp1 * xv[j].y : 0.f;
                const float* ear = eas + idxb[j] * SH_DIM + l * l;
                #pragma unroll
                for (int m = 0; m < 7; ++m)
                    if (m < nm) { acc[m][0] += ear[m] * xt0; acc[m][1] += ear[m] * xt1; }
            }
        }
        __syncthreads();
    }
    unsigned short* mout = msgbf + (size_t)n * (SH_DIM * C_DIM) + (size_t)(l * l) * C_DIM + c0;
    #pragma unroll
    for (int m = 0; m < 7; ++m)
        if (m < nm) *(unsigned int*)(mout + (size_t)m * C_DIM) = packbf2(acc[m][0], acc[m][1]);
}

// ---------------- fallback fused gather (h3 bf16, perm-ordered; msg bf16 out) ----------------
__global__ __launch_bounds__(512, 4) void fused_gather_kernel(
    const int* __restrict__ perm, const int* __restrict__ offs,
    const int* __restrict__ sender, const float* __restrict__ x,
    const float* __restrict__ edge_attrs, const unsigned short* __restrict__ h3,
    const float* __restrict__ w4, unsigned short* __restrict__ msgbf)
{
    int n = blockIdx.x, t = threadIdx.x;
    int c = t & 127, l = t >> 7;
    float wc[RAD_H];
    #pragma unroll
    for (int k = 0; k < RAD_H; ++k)
        wc[k] = w4[k * (NL * C_DIM) + l * C_DIM + c];

    float acc[7] = {0.f, 0.f, 0.f, 0.f, 0.f, 0.f, 0.f};
    int nm = 2 * l + 1;
    int start = offs[n], end = offs[n + 1];
    if (start < end) {
        int e = __builtin_amdgcn_readfirstlane(perm[start]);
        int s = __builtin_amdgcn_readfirstlane(sender[e]);
        for (int idx = start; idx < end; ++idx) {
            #pragma unroll
            for (int k = 0; k < RAD_H; k += 8)
                asm volatile("" : "+v"(wc[k]), "+v"(wc[k+1]), "+v"(wc[k+2]), "+v"(wc[k+3]),
                                  "+v"(wc[k+4]), "+v"(wc[k+5]), "+v"(wc[k+6]), "+v"(wc[k+7]));
            int e_cur = e, s_cur = s;
            if (idx + 1 < end) {
                e = __builtin_amdgcn_readfirstlane(perm[idx + 1]);
                s = __builtin_amdgcn_readfirstlane(sender[e]);
            }
            const unsigned short* h3r = h3 + (size_t)idx * RAD_H;   // perm-ordered bf16
            float xv = x[(size_t)s_cur * C_DIM + c];
            float tp0 = 0.f, tp1 = 0.f, tp2 = 0.f, tp3 = 0.f;
            #pragma unroll
            for (int q = 0; q < RAD_H / 4; ++q) {
                tp0 += bf16val(h3r[4 * q + 0]) * wc[4 * q + 0];
                tp1 += bf16val(h3r[4 * q + 1]) * wc[4 * q + 1];
                tp2 += bf16val(h3r[4 * q + 2]) * wc[4 * q + 2];
                tp3 += bf16val(h3r[4 * q + 3]) * wc[4 * q + 3];
            }
            float tp = (tp0 + tp1) + (tp2 + tp3);
            float xt = xv * (tp * R_SCALE);
            const float* ear = edge_attrs + (size_t)e_cur * SH_DIM + l * l;
            #pragma unroll
            for (int j = 0; j < 7; ++j)
                if (j < nm) acc[j] += ear[j] * xt;
        }
    }
    unsigned short* mout = msgbf + (size_t)n * (SH_DIM * C_DIM) + (size_t)(l * l) * C_DIM + c;
    #pragma unroll
    for (int j = 0; j < 7; ++j)
        if (j < nm) mout[(size_t)j * C_DIM] = bf16bits(acc[j]);
}

// ---------------- out transform via MFMA v3: bf16 msg staged through LDS ----------------
// Round-30 lesson: direct-from-global A fails here (16 rows x 256B apart per
// wave -> 2.2x read amp, no latency hiding; 54-60us). Restore coalesced LDS
// A-staging (bf16 copy, no convert); LDS 52.2 KB -> 3 blocks/CU.
__global__ __launch_bounds__(256, 2) void out_mfma_kernel(
    const unsigned short* __restrict__ msgbf, float* __restrict__ out,
    const float* __restrict__ w_out)
{
    __shared__ unsigned short As[64 * 136];    // 17.4 KB
    __shared__ unsigned short Bp[128 * 136];   // 34.8 KB
    int l = blockIdx.y, t = threadIdx.x;
    int lane = t & 63, wid = t >> 6;
    const int cnt = 2 * l + 1, ms = l * l;
    const int M = N_NODES * cnt;
    const int ntile = (M + 63) >> 6;
    if (blockIdx.x >= ntile) return;

    for (int idx = t; idx < C_DIM * C_DIM; idx += 256) {
        int k = idx >> 7, n = idx & 127;
        Bp[n * 136 + k] = bf16bits(w_out[((size_t)l * C_DIM + k) * C_DIM + n] * OUT_SCALE);
    }
    __syncthreads();

    for (int tile = blockIdx.x; tile < ntile; tile += gridDim.x) {
        int i0 = tile << 6;
        {   // stage A rows: coalesced bf16 copy (4 threads x 64B per 256B row)
            int r = t >> 2, q = t & 3;
            int g = min(i0 + r, M - 1);
            int node = g / cnt, mm = ms + (g - node * cnt);
            const unsigned short* src = msgbf + ((size_t)node * SH_DIM + mm) * C_DIM + q * 32;
            *(short8*)&As[r * 136 + q * 32 + 0]  = *(const short8*)(src + 0);
            *(short8*)&As[r * 136 + q * 32 + 8]  = *(const short8*)(src + 8);
            *(short8*)&As[r * 136 + q * 32 + 16] = *(const short8*)(src + 16);
            *(short8*)&As[r * 136 + q * 32 + 24] = *(const short8*)(src + 24);
        }
        __syncthreads();

        f32x4 acc[8] = {};
        #pragma unroll
        for (int ks = 0; ks < 4; ++ks) {
            short8 a = *(const short8*)&As[(wid * 16 + (lane & 15)) * 136 + ks * 32 + (lane >> 4) * 8];
            #pragma unroll
            for (int f = 0; f < 8; ++f) {
                short8 b = *(const short8*)&Bp[(f * 16 + (lane & 15)) * 136 + ks * 32 + (lane >> 4) * 8];
                acc[f] = __builtin_amdgcn_mfma_f32_16x16x32_bf16(a, b, acc[f], 0, 0, 0);
            }
        }
        __syncthreads();    // all A reads done before next iter's staging

        #pragma unroll
        for (int r = 0; r < 4; ++r) {
            int g = i0 + wid * 16 + (lane >> 4) * 4 + r;
            if (g < M) {
                int node = g / cnt, mm = ms + (g - node * cnt);
                float* dst = out + ((size_t)node * SH_DIM + mm) * C_DIM + (lane & 15);
                #pragma unroll
                for (int f = 0; f < 8; ++f)
                    dst[f * 16] = acc[f][r];
            }
        }
    }
}

extern "C" void kernel_launch(void* const* d_in, const int* in_sizes, int n_in,
                              void* d_out, int out_size, void* d_ws, size_t ws_size,
                              hipStream_t stream)
{
    const float* node_attrs = (const float*)d_in[0];
    const float* node_feats = (const float*)d_in[1];
    const float* edge_attrs = (const float*)d_in[2];
    const float* edge_feats = (const float*)d_in[3];
    const int*   edge_index = (const int*)d_in[4];
    const float* w_up   = (const float*)d_in[5];
    const float* w_rad1 = (const float*)d_in[6];
    const float* w_rad2 = (const float*)d_in[7];
    const float* w_rad3 = (const float*)d_in[8];
    const float* w_rad4 = (const float*)d_in[9];
    const float* w_skip = (const float*)d_in[10];
    const float* w_out  = (const float*)d_in[11];
    const int* sender = edge_index;
    const int* recv   = edge_index + N_EDGE;

    float* out = (float*)d_out;
    float* sc  = out + (size_t)N_NODES * SH_DIM * C_DIM;

    // workspace layout (~147 MB; ws >= 233.4 MB proven)
    float* x   = (float*)d_ws;
    unsigned short* h3 = (unsigned short*)(x + (size_t)N_NODES * C_DIM);  // bf16, perm-ordered
    int* deg    = (int*)(h3 + (size_t)N_EDGE * RAD_H);
    int* cursor = deg + 5120;
    int* offs   = cursor + 5120;
    int* perm   = offs + 5124;
    int* pos_of = perm + N_EDGE;
    __hip_bfloat16* tpw = (__hip_bfloat16*)(pos_of + N_EDGE);
    int* sid_arr = (int*)(tpw + (size_t)N_EDGE * NL * C_DIM);
    float* ea_perm = (float*)(sid_arr + N_EDGE);
    unsigned short* msgbf = (unsigned short*)(ea_perm + (size_t)N_EDGE * SH_DIM);  // 20.5 MB
    size_t need = (size_t)((char*)(msgbf + (size_t)N_NODES * SH_DIM * C_DIM) - (char*)d_ws);
    int mode = (ws_size >= need) ? 1 : 0;

    hipMemsetAsync(deg, 0, 2 * 5120 * sizeof(int), stream);

    node_kernel<<<N_NODES, 128, 0, stream>>>(node_attrs, node_feats, w_skip, w_up, x, sc);

    // CSR build BEFORE radial (radial writes h3 in perm order via pos_of)
    hist_kernel<<<(N_EDGE + 255) / 256, 256, 0, stream>>>(recv, deg);
    scan_kernel<<<1, 256, 0, stream>>>(deg, offs);
    scatter_kernel<<<(N_EDGE + 255) / 256, 256, 0, stream>>>(recv, offs, cursor, perm, pos_of);

    radial_mfma_kernel<<<391, 256, 0, stream>>>(edge_feats, pos_of, w_rad1, w_rad2, w_rad3, h3);

    if (mode == 1) {
        reorder_kernel<<<(N_EDGE + 255) / 256, 256, 0, stream>>>(perm, sender, edge_attrs, sid_arr, (float4*)ea_perm);
        tpw_gemm_kernel<<<dim3(391, 4), 256, 0, stream>>>(h3, w_rad4, tpw);
        stream_gather_kernel<<<N_NODES, 256, 0, stream>>>(offs, sid_arr, x, ea_perm, tpw, msgbf);
        out_mfma_kernel<<<dim3(547, 4), 256, 0, stream>>>(msgbf, out, w_out);
    } else {
        unsigned short* msgbf_fb = (unsigned short*)tpw;
        fused_gather_kernel<<<N_NODES, 512, 0, stream>>>(perm, offs, sender, x, edge_attrs, h3, w_rad4, msgbf_fb);
        out_mfma_kernel<<<dim3(547, 4), 256, 0, stream>>>(msgbf_fb, out, w_out);
    }
}

// Round 32
// 184.114 us; speedup vs baseline: 1.2075x; 1.0340x over previous
//
#include <hip/hip_runtime.h>
#include <hip/hip_bf16.h>
#include <math.h>

#define N_NODES 5000
#define N_ELEMS 10
#define C_DIM   128
#define N_EDGE  100000
#define N_BES   8
#define RAD_H   64
#define NL      4
#define SH_DIM  16
#define TPW_ROWS 64

// scales
#define SC_SCALE 0.02795084971874737f    // 1/sqrt(128*10)
#define X_SCALE  0.08838834764831845f    // 1/sqrt(128)
#define R1_SCALE 0.3535533905932738f     // 1/sqrt(8)
#define R_SCALE  0.125f                  // 1/sqrt(64)
#define OUT_SCALE 0.004419417382415922f  // (1/sqrt(128))/20

typedef __attribute__((ext_vector_type(8))) short short8;
typedef __attribute__((ext_vector_type(4))) float f32x4;

__device__ __forceinline__ float silu(float v) { return v / (1.f + __expf(-v)); }
__device__ __forceinline__ unsigned short bf16bits(float v) {
    __hip_bfloat16 h = __float2bfloat16(v);
    return *(unsigned short*)&h;
}
__device__ __forceinline__ float bf16val(unsigned short b) {
    unsigned int u = ((unsigned int)b) << 16;
    return __uint_as_float(u);
}
__device__ __forceinline__ unsigned int packbf2(float lo, float hi) {
    return (unsigned int)bf16bits(lo) | ((unsigned int)bf16bits(hi) << 16);
}

// ---------------- node kernel: sc + x ----------------
__global__ __launch_bounds__(128) void node_kernel(
    const float* __restrict__ node_attrs, const float* __restrict__ node_feats,
    const float* __restrict__ w_skip, const float* __restrict__ w_up,
    float* __restrict__ x, float* __restrict__ sc_out)
{
    int n = blockIdx.x, t = threadIdx.x;
    __shared__ float f[C_DIM];
    __shared__ float at[N_ELEMS];
    f[t] = node_feats[(size_t)n * C_DIM + t];
    if (t < N_ELEMS) at[t] = node_attrs[(size_t)n * N_ELEMS + t];
    __syncthreads();

    float acc = 0.f;
    for (int a = 0; a < N_ELEMS; ++a) {
        float av = at[a];
        if (av != 0.f) {
            const float* wp = w_skip + a * C_DIM + t;
            float s2 = 0.f;
            #pragma unroll 8
            for (int c = 0; c < C_DIM; ++c) s2 += f[c] * wp[(size_t)c * (N_ELEMS * C_DIM)];
            acc += av * s2;
        }
    }
    sc_out[(size_t)n * C_DIM + t] = acc * SC_SCALE;

    float xa = 0.f;
    #pragma unroll 8
    for (int k = 0; k < C_DIM; ++k) xa += f[k] * w_up[k * C_DIM + t];
    x[(size_t)n * C_DIM + t] = xa * X_SCALE;
}

// ---------------- radial MLP v6: MFMA layers 2+3, h3 bf16 perm order ----------------
// Round-31 fix: was grid-starved (391 blocks < 512 resident capacity).
// Grid 1563 (1 tile/block) + (256,4) occupancy.
__global__ __launch_bounds__(256, 4) void radial_mfma_kernel(
    const float* __restrict__ edge_feats, const int* __restrict__ pos_of,
    const float* __restrict__ w1, const float* __restrict__ w2, const float* __restrict__ w3,
    unsigned short* __restrict__ h3out)
{
    __shared__ unsigned short As[64 * 72];
    __shared__ unsigned short w2t[64 * 72];
    __shared__ unsigned short w3t[64 * 72];
    int t = threadIdx.x;
    int lane = t & 63, wid = t >> 6;

    for (int idx = t; idx < RAD_H * RAD_H; idx += 256) {
        int k = idx >> 6, n = idx & 63;
        w2t[n * 72 + k] = bf16bits(w2[k * RAD_H + n] * R_SCALE);
        w3t[n * 72 + k] = bf16bits(w3[k * RAD_H + n] * R_SCALE);
    }
    __syncthreads();

    short8 b2[2][4], b3[2][4];
    #pragma unroll
    for (int s = 0; s < 2; ++s)
        #pragma unroll
        for (int f = 0; f < 4; ++f) {
            b2[s][f] = *(const short8*)&w2t[(f * 16 + (lane & 15)) * 72 + s * 32 + (lane >> 4) * 8];
            b3[s][f] = *(const short8*)&w3t[(f * 16 + (lane & 15)) * 72 + s * 32 + (lane >> 4) * 8];
        }

    float w1r[N_BES];
    #pragma unroll
    for (int k = 0; k < N_BES; ++k) w1r[k] = w1[k * RAD_H + lane] * R1_SCALE;

    const int ntiles = (N_EDGE + 63) >> 6;
    for (int tile = blockIdx.x; tile < ntiles; tile += gridDim.x) {
        int i0 = tile << 6;
        int ebase = __builtin_amdgcn_readfirstlane(i0 + wid * 16);

        #pragma unroll 4
        for (int ee = 0; ee < 16; ++ee) {
            int e = min(ebase + ee, N_EDGE - 1);
            const float* ef = edge_feats + (size_t)e * N_BES;
            float a = 0.f;
            #pragma unroll
            for (int k = 0; k < N_BES; ++k) a += ef[k] * w1r[k];
            As[(wid * 16 + ee) * 72 + lane] = bf16bits(silu(a));
        }
        __builtin_amdgcn_wave_barrier();

        {
            short8 a0 = *(const short8*)&As[(wid * 16 + (lane & 15)) * 72 + 0 * 32 + (lane >> 4) * 8];
            short8 a1 = *(const short8*)&As[(wid * 16 + (lane & 15)) * 72 + 1 * 32 + (lane >> 4) * 8];
            f32x4 acc[4] = {};
            #pragma unroll
            for (int f = 0; f < 4; ++f) {
                acc[f] = __builtin_amdgcn_mfma_f32_16x16x32_bf16(a0, b2[0][f], acc[f], 0, 0, 0);
                acc[f] = __builtin_amdgcn_mfma_f32_16x16x32_bf16(a1, b2[1][f], acc[f], 0, 0, 0);
            }
            __builtin_amdgcn_wave_barrier();
            #pragma unroll
            for (int f = 0; f < 4; ++f)
                #pragma unroll
                for (int r = 0; r < 4; ++r)
                    As[(wid * 16 + (lane >> 4) * 4 + r) * 72 + f * 16 + (lane & 15)] =
                        bf16bits(silu(acc[f][r]));
        }
        __builtin_amdgcn_wave_barrier();

        {
            short8 a0 = *(const short8*)&As[(wid * 16 + (lane & 15)) * 72 + 0 * 32 + (lane >> 4) * 8];
            short8 a1 = *(const short8*)&As[(wid * 16 + (lane & 15)) * 72 + 1 * 32 + (lane >> 4) * 8];
            f32x4 acc[4] = {};
            #pragma unroll
            for (int f = 0; f < 4; ++f) {
                acc[f] = __builtin_amdgcn_mfma_f32_16x16x32_bf16(a0, b3[0][f], acc[f], 0, 0, 0);
                acc[f] = __builtin_amdgcn_mfma_f32_16x16x32_bf16(a1, b3[1][f], acc[f], 0, 0, 0);
            }
            #pragma unroll
            for (int r = 0; r < 4; ++r) {
                int e = i0 + wid * 16 + (lane >> 4) * 4 + r;
                if (e < N_EDGE) {
                    int row = pos_of[e];             // perm-ordered destination
                    unsigned short* dst = h3out + (size_t)row * RAD_H + (lane & 15);
                    #pragma unroll
                    for (int f = 0; f < 4; ++f)
                        dst[f * 16] = bf16bits(silu(acc[f][r]));
                }
            }
        }
        __builtin_amdgcn_wave_barrier();
    }
}

// ---------------- CSR build ----------------
__global__ void hist_kernel(const int* __restrict__ recv, int* __restrict__ deg)
{
    int e = blockIdx.x * 256 + threadIdx.x;
    if (e < N_EDGE) atomicAdd(&deg[recv[e]], 1);
}

__global__ __launch_bounds__(256) void scan_kernel(const int* __restrict__ deg, int* __restrict__ offs)
{
    __shared__ int sums[256];
    int t = threadIdx.x;
    int base = t * 20;
    int loc[20]; int s = 0;
    #pragma unroll
    for (int i = 0; i < 20; ++i) { int idx = base + i; int v = (idx < N_NODES) ? deg[idx] : 0; loc[i] = s; s += v; }
    sums[t] = s; __syncthreads();
    for (int off = 1; off < 256; off <<= 1) {
        int v = (t >= off) ? sums[t - off] : 0;
        __syncthreads();
        sums[t] += v;
        __syncthreads();
    }
    int ex = (t == 0) ? 0 : sums[t - 1];
    #pragma unroll
    for (int i = 0; i < 20; ++i) { int idx = base + i; if (idx < N_NODES) offs[idx] = ex + loc[i]; }
    if (t == 255) offs[N_NODES] = sums[255];
}

// scatter also records pos_of[e] = CSR index (inverse perm)
__global__ void scatter_kernel(const int* __restrict__ recv, const int* __restrict__ offs,
                               int* __restrict__ cursor, int* __restrict__ perm,
                               int* __restrict__ pos_of)
{
    int e = blockIdx.x * 256 + threadIdx.x;
    if (e < N_EDGE) {
        int r = recv[e];
        int pos = atomicAdd(&cursor[r], 1);
        int idx = offs[r] + pos;
        perm[idx] = e;
        pos_of[e] = idx;
    }
}

// ---------------- reorder: sid_arr[idx]=sender[perm[idx]], ea_perm[idx]=edge_attrs[perm[idx]] ----------------
__global__ void reorder_kernel(const int* __restrict__ perm, const int* __restrict__ sender,
                               const float* __restrict__ edge_attrs,
                               int* __restrict__ sid_arr, float4* __restrict__ ea_perm4)
{
    int idx = blockIdx.x * 256 + threadIdx.x;
    if (idx < N_EDGE) {
        int e = perm[idx];
        sid_arr[idx] = sender[e];
        const float4* src = (const float4*)(edge_attrs + (size_t)e * SH_DIM);
        float4* dst = ea_perm4 + (size_t)idx * 4;
        dst[0] = src[0]; dst[1] = src[1]; dst[2] = src[2]; dst[3] = src[3];
    }
}

// ---------------- tpw GEMM via MFMA: A-fragments DIRECT FROM GLOBAL (bf16 h3) ----------------
__global__ __launch_bounds__(256, 4) void tpw_gemm_kernel(
    const unsigned short* __restrict__ h3, const float* __restrict__ w4,
    __hip_bfloat16* __restrict__ tpw)
{
    __shared__ unsigned short uni[64 * 136];  // epi buffer only (17.4 KB)
    __shared__ unsigned short Bp[128 * 72];   // [n][k] pad 8 (18.4 KB)
    int l = blockIdx.y, t = threadIdx.x;
    int lane = t & 63, wid = t >> 6;

    for (int idx = t; idx < RAD_H * C_DIM; idx += 256) {
        int k = idx >> 7, n = idx & 127;
        Bp[n * 72 + k] = bf16bits(w4[k * (NL * C_DIM) + l * C_DIM + n] * R_SCALE);
    }
    __syncthreads();

    short8 bfr[2][8];
    #pragma unroll
    for (int s = 0; s < 2; ++s)
        #pragma unroll
        for (int f = 0; f < 8; ++f)
            bfr[s][f] = *(const short8*)&Bp[(f * 16 + (lane & 15)) * 72 + s * 32 + (lane >> 4) * 8];

    const int ntiles = (N_EDGE + TPW_ROWS - 1) / TPW_ROWS;   // 1563
    short8 a_cur[2];
    {
        int arow = min((int)blockIdx.x * TPW_ROWS + wid * 16 + (lane & 15), N_EDGE - 1);
        a_cur[0] = *(const short8*)&h3[(size_t)arow * RAD_H + 0 * 32 + (lane >> 4) * 8];
        a_cur[1] = *(const short8*)&h3[(size_t)arow * RAD_H + 1 * 32 + (lane >> 4) * 8];
    }
    for (int tile = blockIdx.x; tile < ntiles; tile += gridDim.x) {
        int i0 = tile * TPW_ROWS;
        short8 a_nxt[2];
        int ntile2 = tile + gridDim.x;
        if (ntile2 < ntiles) {
            int arow = min(ntile2 * TPW_ROWS + wid * 16 + (lane & 15), N_EDGE - 1);
            a_nxt[0] = *(const short8*)&h3[(size_t)arow * RAD_H + 0 * 32 + (lane >> 4) * 8];
            a_nxt[1] = *(const short8*)&h3[(size_t)arow * RAD_H + 1 * 32 + (lane >> 4) * 8];
        }

        f32x4 acc[8] = {};
        #pragma unroll
        for (int s = 0; s < 2; ++s)
            #pragma unroll
            for (int f = 0; f < 8; ++f)
                acc[f] = __builtin_amdgcn_mfma_f32_16x16x32_bf16(a_cur[s], bfr[s][f], acc[f], 0, 0, 0);

        __syncthreads();    // prev copy-out done before epi overwrite
        #pragma unroll
        for (int f = 0; f < 8; ++f)
            #pragma unroll
            for (int r = 0; r < 4; ++r)
                uni[(wid * 16 + (lane >> 4) * 4 + r) * 136 + f * 16 + (lane & 15)] = bf16bits(acc[f][r]);
        __syncthreads();    // epi ready

        {
            int row = t >> 2, q = t & 3;
            if (i0 + row < N_EDGE) {
                unsigned short* dst = (unsigned short*)tpw + (size_t)(i0 + row) * (NL * C_DIM) + l * C_DIM + q * 32;
                #pragma unroll
                for (int v = 0; v < 4; ++v)
                    *(short8*)(dst + v * 8) = *(const short8*)&uni[row * 136 + q * 32 + v * 8];
            }
        }
        a_cur[0] = a_nxt[0];
        a_cur[1] = a_nxt[1];
    }
}

// ---------------- stream gather v6: msg written as BF16 (feeds out_mfma) ----------------
__global__ __launch_bounds__(256, 4) void stream_gather_kernel(
    const int* __restrict__ offs, const int* __restrict__ sid_arr,
    const float* __restrict__ x, const float* __restrict__ ea_perm,
    const __hip_bfloat16* __restrict__ tpw, unsigned short* __restrict__ msgbf)
{
    __shared__ float eas[128 * SH_DIM];   // 8 KB
    __shared__ int   sids[128];
    int n = blockIdx.x, t = threadIdx.x;
    int cq = t & 63, l = t >> 6;
    int c0 = cq * 2;
    float acc[7][2] = {};
    int nm = 2 * l + 1;
    int start = offs[n], end = offs[n + 1];

    for (int cs = start; cs < end; cs += 128) {
        int clen = min(128, end - cs);
        {
            const float4* src = (const float4*)(ea_perm + (size_t)cs * SH_DIM);
            float4* dst = (float4*)eas;
            for (int i = t; i < clen * 4; i += 256) dst[i] = src[i];
            for (int i = t; i < clen; i += 256) sids[i] = sid_arr[cs + i];
        }
        __syncthreads();

        for (int base = 0; base < clen; base += 8) {
            int idxb[8], sidb[8];
            #pragma unroll
            for (int j = 0; j < 8; ++j) idxb[j] = min(base + j, clen - 1);
            #pragma unroll
            for (int j = 0; j < 8; ++j) sidb[j] = sids[idxb[j]];

            unsigned int tpb[8];
            float2 xv[8];
            #pragma unroll
            for (int j = 0; j < 8; ++j)
                tpb[j] = *(const unsigned int*)((const unsigned short*)tpw
                          + (size_t)(cs + idxb[j]) * (NL * C_DIM) + l * C_DIM + c0);
            #pragma unroll
            for (int j = 0; j < 8; ++j)
                xv[j] = *(const float2*)(x + (size_t)sidb[j] * C_DIM + c0);
            asm volatile("" : "+v"(tpb[0]), "+v"(tpb[1]), "+v"(tpb[2]), "+v"(tpb[3]),
                              "+v"(tpb[4]), "+v"(tpb[5]), "+v"(tpb[6]), "+v"(tpb[7]),
                              "+v"(xv[0].x), "+v"(xv[0].y), "+v"(xv[1].x), "+v"(xv[1].y),
                              "+v"(xv[2].x), "+v"(xv[2].y), "+v"(xv[3].x), "+v"(xv[3].y),
                              "+v"(xv[4].x), "+v"(xv[4].y), "+v"(xv[5].x), "+v"(xv[5].y),
                              "+v"(xv[6].x), "+v"(xv[6].y), "+v"(xv[7].x), "+v"(xv[7].y));

            #pragma unroll
            for (int j = 0; j < 8; ++j) {
                unsigned int lo = (tpb[j] & 0xFFFFu) << 16;
                unsigned int hi = tpb[j] & 0xFFFF0000u;
                float tp0 = __uint_as_float(lo);
                float tp1 = __uint_as_float(hi);
                bool valid = (base + j < clen);
                float xt0 = valid ? tp0 * xv[j].x : 0.f;
                float xt1 = valid ? tp1 * xv[j].y : 0.f;
                const float* ear = eas + idxb[j] * SH_DIM + l * l;
                #pragma unroll
                for (int m = 0; m < 7; ++m)
                    if (m < nm) { acc[m][0] += ear[m] * xt0; acc[m][1] += ear[m] * xt1; }
            }
        }
        __syncthreads();
    }
    unsigned short* mout = msgbf + (size_t)n * (SH_DIM * C_DIM) + (size_t)(l * l) * C_DIM + c0;
    #pragma unroll
    for (int m = 0; m < 7; ++m)
        if (m < nm) *(unsigned int*)(mout + (size_t)m * C_DIM) = packbf2(acc[m][0], acc[m][1]);
}

// ---------------- fallback fused gather (h3 bf16, perm-ordered; msg bf16 out) ----------------
__global__ __launch_bounds__(512, 4) void fused_gather_kernel(
    const int* __restrict__ perm, const int* __restrict__ offs,
    const int* __restrict__ sender, const float* __restrict__ x,
    const float* __restrict__ edge_attrs, const unsigned short* __restrict__ h3,
    const float* __restrict__ w4, unsigned short* __restrict__ msgbf)
{
    int n = blockIdx.x, t = threadIdx.x;
    int c = t & 127, l = t >> 7;
    float wc[RAD_H];
    #pragma unroll
    for (int k = 0; k < RAD_H; ++k)
        wc[k] = w4[k * (NL * C_DIM) + l * C_DIM + c];

    float acc[7] = {0.f, 0.f, 0.f, 0.f, 0.f, 0.f, 0.f};
    int nm = 2 * l + 1;
    int start = offs[n], end = offs[n + 1];
    if (start < end) {
        int e = __builtin_amdgcn_readfirstlane(perm[start]);
        int s = __builtin_amdgcn_readfirstlane(sender[e]);
        for (int idx = start; idx < end; ++idx) {
            #pragma unroll
            for (int k = 0; k < RAD_H; k += 8)
                asm volatile("" : "+v"(wc[k]), "+v"(wc[k+1]), "+v"(wc[k+2]), "+v"(wc[k+3]),
                                  "+v"(wc[k+4]), "+v"(wc[k+5]), "+v"(wc[k+6]), "+v"(wc[k+7]));
            int e_cur = e, s_cur = s;
            if (idx + 1 < end) {
                e = __builtin_amdgcn_readfirstlane(perm[idx + 1]);
                s = __builtin_amdgcn_readfirstlane(sender[e]);
            }
            const unsigned short* h3r = h3 + (size_t)idx * RAD_H;   // perm-ordered bf16
            float xv = x[(size_t)s_cur * C_DIM + c];
            float tp0 = 0.f, tp1 = 0.f, tp2 = 0.f, tp3 = 0.f;
            #pragma unroll
            for (int q = 0; q < RAD_H / 4; ++q) {
                tp0 += bf16val(h3r[4 * q + 0]) * wc[4 * q + 0];
                tp1 += bf16val(h3r[4 * q + 1]) * wc[4 * q + 1];
                tp2 += bf16val(h3r[4 * q + 2]) * wc[4 * q + 2];
                tp3 += bf16val(h3r[4 * q + 3]) * wc[4 * q + 3];
            }
            float tp = (tp0 + tp1) + (tp2 + tp3);
            float xt = xv * (tp * R_SCALE);
            const float* ear = edge_attrs + (size_t)e_cur * SH_DIM + l * l;
            #pragma unroll
            for (int j = 0; j < 7; ++j)
                if (j < nm) acc[j] += ear[j] * xt;
        }
    }
    unsigned short* mout = msgbf + (size_t)n * (SH_DIM * C_DIM) + (size_t)(l * l) * C_DIM + c;
    #pragma unroll
    for (int j = 0; j < 7; ++j)
        if (j < nm) mout[(size_t)j * C_DIM] = bf16bits(acc[j]);
}

// ---------------- out transform via MFMA v3: bf16 msg staged through LDS ----------------
// Round-31: (256,2) -> (256,3); 52.2 KB LDS allows 3 blocks/CU.
__global__ __launch_bounds__(256, 3) void out_mfma_kernel(
    const unsigned short* __restrict__ msgbf, float* __restrict__ out,
    const float* __restrict__ w_out)
{
    __shared__ unsigned short As[64 * 136];    // 17.4 KB
    __shared__ unsigned short Bp[128 * 136];   // 34.8 KB
    int l = blockIdx.y, t = threadIdx.x;
    int lane = t & 63, wid = t >> 6;
    const int cnt = 2 * l + 1, ms = l * l;
    const int M = N_NODES * cnt;
    const int ntile = (M + 63) >> 6;
    if (blockIdx.x >= ntile) return;

    for (int idx = t; idx < C_DIM * C_DIM; idx += 256) {
        int k = idx >> 7, n = idx & 127;
        Bp[n * 136 + k] = bf16bits(w_out[((size_t)l * C_DIM + k) * C_DIM + n] * OUT_SCALE);
    }
    __syncthreads();

    for (int tile = blockIdx.x; tile < ntile; tile += gridDim.x) {
        int i0 = tile << 6;
        {   // stage A rows: coalesced bf16 copy (4 threads x 64B per 256B row)
            int r = t >> 2, q = t & 3;
            int g = min(i0 + r, M - 1);
            int node = g / cnt, mm = ms + (g - node * cnt);
            const unsigned short* src = msgbf + ((size_t)node * SH_DIM + mm) * C_DIM + q * 32;
            *(short8*)&As[r * 136 + q * 32 + 0]  = *(const short8*)(src + 0);
            *(short8*)&As[r * 136 + q * 32 + 8]  = *(const short8*)(src + 8);
            *(short8*)&As[r * 136 + q * 32 + 16] = *(const short8*)(src + 16);
            *(short8*)&As[r * 136 + q * 32 + 24] = *(const short8*)(src + 24);
        }
        __syncthreads();

        f32x4 acc[8] = {};
        #pragma unroll
        for (int ks = 0; ks < 4; ++ks) {
            short8 a = *(const short8*)&As[(wid * 16 + (lane & 15)) * 136 + ks * 32 + (lane >> 4) * 8];
            #pragma unroll
            for (int f = 0; f < 8; ++f) {
                short8 b = *(const short8*)&Bp[(f * 16 + (lane & 15)) * 136 + ks * 32 + (lane >> 4) * 8];
                acc[f] = __builtin_amdgcn_mfma_f32_16x16x32_bf16(a, b, acc[f], 0, 0, 0);
            }
        }
        __syncthreads();    // all A reads done before next iter's staging

        #pragma unroll
        for (int r = 0; r < 4; ++r) {
            int g = i0 + wid * 16 + (lane >> 4) * 4 + r;
            if (g < M) {
                int node = g / cnt, mm = ms + (g - node * cnt);
                float* dst = out + ((size_t)node * SH_DIM + mm) * C_DIM + (lane & 15);
                #pragma unroll
                for (int f = 0; f < 8; ++f)
                    dst[f * 16] = acc[f][r];
            }
        }
    }
}

extern "C" void kernel_launch(void* const* d_in, const int* in_sizes, int n_in,
                              void* d_out, int out_size, void* d_ws, size_t ws_size,
                              hipStream_t stream)
{
    const float* node_attrs = (const float*)d_in[0];
    const float* node_feats = (const float*)d_in[1];
    const float* edge_attrs = (const float*)d_in[2];
    const float* edge_feats = (const float*)d_in[3];
    const int*   edge_index = (const int*)d_in[4];
    const float* w_up   = (const float*)d_in[5];
    const float* w_rad1 = (const float*)d_in[6];
    const float* w_rad2 = (const float*)d_in[7];
    const float* w_rad3 = (const float*)d_in[8];
    const float* w_rad4 = (const float*)d_in[9];
    const float* w_skip = (const float*)d_in[10];
    const float* w_out  = (const float*)d_in[11];
    const int* sender = edge_index;
    const int* recv   = edge_index + N_EDGE;

    float* out = (float*)d_out;
    float* sc  = out + (size_t)N_NODES * SH_DIM * C_DIM;

    // workspace layout (~147 MB; ws >= 233.4 MB proven)
    float* x   = (float*)d_ws;
    unsigned short* h3 = (unsigned short*)(x + (size_t)N_NODES * C_DIM);  // bf16, perm-ordered
    int* deg    = (int*)(h3 + (size_t)N_EDGE * RAD_H);
    int* cursor = deg + 5120;
    int* offs   = cursor + 5120;
    int* perm   = offs + 5124;
    int* pos_of = perm + N_EDGE;
    __hip_bfloat16* tpw = (__hip_bfloat16*)(pos_of + N_EDGE);
    int* sid_arr = (int*)(tpw + (size_t)N_EDGE * NL * C_DIM);
    float* ea_perm = (float*)(sid_arr + N_EDGE);
    unsigned short* msgbf = (unsigned short*)(ea_perm + (size_t)N_EDGE * SH_DIM);  // 20.5 MB
    size_t need = (size_t)((char*)(msgbf + (size_t)N_NODES * SH_DIM * C_DIM) - (char*)d_ws);
    int mode = (ws_size >= need) ? 1 : 0;

    hipMemsetAsync(deg, 0, 2 * 5120 * sizeof(int), stream);

    node_kernel<<<N_NODES, 128, 0, stream>>>(node_attrs, node_feats, w_skip, w_up, x, sc);

    // CSR build BEFORE radial (radial writes h3 in perm order via pos_of)
    hist_kernel<<<(N_EDGE + 255) / 256, 256, 0, stream>>>(recv, deg);
    scan_kernel<<<1, 256, 0, stream>>>(deg, offs);
    scatter_kernel<<<(N_EDGE + 255) / 256, 256, 0, stream>>>(recv, offs, cursor, perm, pos_of);

    radial_mfma_kernel<<<1563, 256, 0, stream>>>(edge_feats, pos_of, w_rad1, w_rad2, w_rad3, h3);

    if (mode == 1) {
        reorder_kernel<<<(N_EDGE + 255) / 256, 256, 0, stream>>>(perm, sender, edge_attrs, sid_arr, (float4*)ea_perm);
        tpw_gemm_kernel<<<dim3(391, 4), 256, 0, stream>>>(h3, w_rad4, tpw);
        stream_gather_kernel<<<N_NODES, 256, 0, stream>>>(offs, sid_arr, x, ea_perm, tpw, msgbf);
        out_mfma_kernel<<<dim3(547, 4), 256, 0, stream>>>(msgbf, out, w_out);
    } else {
        unsigned short* msgbf_fb = (unsigned short*)tpw;
        fused_gather_kernel<<<N_NODES, 512, 0, stream>>>(perm, offs, sender, x, edge_attrs, h3, w_rad4, msgbf_fb);
        out_mfma_kernel<<<dim3(547, 4), 256, 0, stream>>>(msgbf_fb, out, w_out);
    }
}

// Round 33
// 184.006 us; speedup vs baseline: 1.2082x; 1.0006x over previous
//
#include <hip/hip_runtime.h>
#include <hip/hip_bf16.h>
#include <math.h>

#define N_NODES 5000
#define N_ELEMS 10
#define C_DIM   128
#define N_EDGE  100000
#define N_BES   8
#define RAD_H   64
#define NL      4
#define SH_DIM  16
#define TPW_ROWS 64

// scales
#define SC_SCALE 0.02795084971874737f    // 1/sqrt(128*10)
#define X_SCALE  0.08838834764831845f    // 1/sqrt(128)
#define R1_SCALE 0.3535533905932738f     // 1/sqrt(8)
#define R_SCALE  0.125f                  // 1/sqrt(64)
#define OUT_SCALE 0.004419417382415922f  // (1/sqrt(128))/20

typedef __attribute__((ext_vector_type(8))) short short8;
typedef __attribute__((ext_vector_type(4))) float f32x4;

__device__ __forceinline__ float silu(float v) { return v / (1.f + __expf(-v)); }
__device__ __forceinline__ unsigned short bf16bits(float v) {
    __hip_bfloat16 h = __float2bfloat16(v);
    return *(unsigned short*)&h;
}
__device__ __forceinline__ float bf16val(unsigned short b) {
    unsigned int u = ((unsigned int)b) << 16;
    return __uint_as_float(u);
}
__device__ __forceinline__ unsigned int packbf2(float lo, float hi) {
    return (unsigned int)bf16bits(lo) | ((unsigned int)bf16bits(hi) << 16);
}

// ---------------- node kernel: sc + x ----------------
__global__ __launch_bounds__(128) void node_kernel(
    const float* __restrict__ node_attrs, const float* __restrict__ node_feats,
    const float* __restrict__ w_skip, const float* __restrict__ w_up,
    float* __restrict__ x, float* __restrict__ sc_out)
{
    int n = blockIdx.x, t = threadIdx.x;
    __shared__ float f[C_DIM];
    __shared__ float at[N_ELEMS];
    f[t] = node_feats[(size_t)n * C_DIM + t];
    if (t < N_ELEMS) at[t] = node_attrs[(size_t)n * N_ELEMS + t];
    __syncthreads();

    float acc = 0.f;
    for (int a = 0; a < N_ELEMS; ++a) {
        float av = at[a];
        if (av != 0.f) {
            const float* wp = w_skip + a * C_DIM + t;
            float s2 = 0.f;
            #pragma unroll 8
            for (int c = 0; c < C_DIM; ++c) s2 += f[c] * wp[(size_t)c * (N_ELEMS * C_DIM)];
            acc += av * s2;
        }
    }
    sc_out[(size_t)n * C_DIM + t] = acc * SC_SCALE;

    float xa = 0.f;
    #pragma unroll 8
    for (int k = 0; k < C_DIM; ++k) xa += f[k] * w_up[k * C_DIM + t];
    x[(size_t)n * C_DIM + t] = xa * X_SCALE;
}

// ---------------- radial MLP v6: MFMA layers 2+3, h3 bf16 perm order ----------------
__global__ __launch_bounds__(256, 4) void radial_mfma_kernel(
    const float* __restrict__ edge_feats, const int* __restrict__ pos_of,
    const float* __restrict__ w1, const float* __restrict__ w2, const float* __restrict__ w3,
    unsigned short* __restrict__ h3out)
{
    __shared__ unsigned short As[64 * 72];
    __shared__ unsigned short w2t[64 * 72];
    __shared__ unsigned short w3t[64 * 72];
    int t = threadIdx.x;
    int lane = t & 63, wid = t >> 6;

    for (int idx = t; idx < RAD_H * RAD_H; idx += 256) {
        int k = idx >> 6, n = idx & 63;
        w2t[n * 72 + k] = bf16bits(w2[k * RAD_H + n] * R_SCALE);
        w3t[n * 72 + k] = bf16bits(w3[k * RAD_H + n] * R_SCALE);
    }
    __syncthreads();

    short8 b2[2][4], b3[2][4];
    #pragma unroll
    for (int s = 0; s < 2; ++s)
        #pragma unroll
        for (int f = 0; f < 4; ++f) {
            b2[s][f] = *(const short8*)&w2t[(f * 16 + (lane & 15)) * 72 + s * 32 + (lane >> 4) * 8];
            b3[s][f] = *(const short8*)&w3t[(f * 16 + (lane & 15)) * 72 + s * 32 + (lane >> 4) * 8];
        }

    float w1r[N_BES];
    #pragma unroll
    for (int k = 0; k < N_BES; ++k) w1r[k] = w1[k * RAD_H + lane] * R1_SCALE;

    const int ntiles = (N_EDGE + 63) >> 6;
    for (int tile = blockIdx.x; tile < ntiles; tile += gridDim.x) {
        int i0 = tile << 6;
        int ebase = __builtin_amdgcn_readfirstlane(i0 + wid * 16);

        #pragma unroll 4
        for (int ee = 0; ee < 16; ++ee) {
            int e = min(ebase + ee, N_EDGE - 1);
            const float* ef = edge_feats + (size_t)e * N_BES;
            float a = 0.f;
            #pragma unroll
            for (int k = 0; k < N_BES; ++k) a += ef[k] * w1r[k];
            As[(wid * 16 + ee) * 72 + lane] = bf16bits(silu(a));
        }
        __builtin_amdgcn_wave_barrier();

        {
            short8 a0 = *(const short8*)&As[(wid * 16 + (lane & 15)) * 72 + 0 * 32 + (lane >> 4) * 8];
            short8 a1 = *(const short8*)&As[(wid * 16 + (lane & 15)) * 72 + 1 * 32 + (lane >> 4) * 8];
            f32x4 acc[4] = {};
            #pragma unroll
            for (int f = 0; f < 4; ++f) {
                acc[f] = __builtin_amdgcn_mfma_f32_16x16x32_bf16(a0, b2[0][f], acc[f], 0, 0, 0);
                acc[f] = __builtin_amdgcn_mfma_f32_16x16x32_bf16(a1, b2[1][f], acc[f], 0, 0, 0);
            }
            __builtin_amdgcn_wave_barrier();
            #pragma unroll
            for (int f = 0; f < 4; ++f)
                #pragma unroll
                for (int r = 0; r < 4; ++r)
                    As[(wid * 16 + (lane >> 4) * 4 + r) * 72 + f * 16 + (lane & 15)] =
                        bf16bits(silu(acc[f][r]));
        }
        __builtin_amdgcn_wave_barrier();

        {
            short8 a0 = *(const short8*)&As[(wid * 16 + (lane & 15)) * 72 + 0 * 32 + (lane >> 4) * 8];
            short8 a1 = *(const short8*)&As[(wid * 16 + (lane & 15)) * 72 + 1 * 32 + (lane >> 4) * 8];
            f32x4 acc[4] = {};
            #pragma unroll
            for (int f = 0; f < 4; ++f) {
                acc[f] = __builtin_amdgcn_mfma_f32_16x16x32_bf16(a0, b3[0][f], acc[f], 0, 0, 0);
                acc[f] = __builtin_amdgcn_mfma_f32_16x16x32_bf16(a1, b3[1][f], acc[f], 0, 0, 0);
            }
            #pragma unroll
            for (int r = 0; r < 4; ++r) {
                int e = i0 + wid * 16 + (lane >> 4) * 4 + r;
                if (e < N_EDGE) {
                    int row = pos_of[e];             // perm-ordered destination
                    unsigned short* dst = h3out + (size_t)row * RAD_H + (lane & 15);
                    #pragma unroll
                    for (int f = 0; f < 4; ++f)
                        dst[f * 16] = bf16bits(silu(acc[f][r]));
                }
            }
        }
        __builtin_amdgcn_wave_barrier();
    }
}

// ---------------- CSR build ----------------
__global__ void hist_kernel(const int* __restrict__ recv, int* __restrict__ deg)
{
    int e = blockIdx.x * 256 + threadIdx.x;
    if (e < N_EDGE) atomicAdd(&deg[recv[e]], 1);
}

__global__ __launch_bounds__(256) void scan_kernel(const int* __restrict__ deg, int* __restrict__ offs)
{
    __shared__ int sums[256];
    int t = threadIdx.x;
    int base = t * 20;
    int loc[20]; int s = 0;
    #pragma unroll
    for (int i = 0; i < 20; ++i) { int idx = base + i; int v = (idx < N_NODES) ? deg[idx] : 0; loc[i] = s; s += v; }
    sums[t] = s; __syncthreads();
    for (int off = 1; off < 256; off <<= 1) {
        int v = (t >= off) ? sums[t - off] : 0;
        __syncthreads();
        sums[t] += v;
        __syncthreads();
    }
    int ex = (t == 0) ? 0 : sums[t - 1];
    #pragma unroll
    for (int i = 0; i < 20; ++i) { int idx = base + i; if (idx < N_NODES) offs[idx] = ex + loc[i]; }
    if (t == 255) offs[N_NODES] = sums[255];
}

// scatter also records pos_of[e] = CSR index (inverse perm)
__global__ void scatter_kernel(const int* __restrict__ recv, const int* __restrict__ offs,
                               int* __restrict__ cursor, int* __restrict__ perm,
                               int* __restrict__ pos_of)
{
    int e = blockIdx.x * 256 + threadIdx.x;
    if (e < N_EDGE) {
        int r = recv[e];
        int pos = atomicAdd(&cursor[r], 1);
        int idx = offs[r] + pos;
        perm[idx] = e;
        pos_of[e] = idx;
    }
}

// ---------------- reorder: sid_arr[idx]=sender[perm[idx]], ea_perm[idx]=edge_attrs[perm[idx]] ----------------
__global__ void reorder_kernel(const int* __restrict__ perm, const int* __restrict__ sender,
                               const float* __restrict__ edge_attrs,
                               int* __restrict__ sid_arr, float4* __restrict__ ea_perm4)
{
    int idx = blockIdx.x * 256 + threadIdx.x;
    if (idx < N_EDGE) {
        int e = perm[idx];
        sid_arr[idx] = sender[e];
        const float4* src = (const float4*)(edge_attrs + (size_t)e * SH_DIM);
        float4* dst = ea_perm4 + (size_t)idx * 4;
        dst[0] = src[0]; dst[1] = src[1]; dst[2] = src[2]; dst[3] = src[3];
    }
}

// ---------------- tpw GEMM via MFMA: l-MAJOR tpw planes ----------------
// Round-32 change: tpw layout [l][edge][128]. Each l-plane is a contiguous
// write stream owned entirely by that l's blocks -> full-line writes (was:
// four blocks interleave 256B quarters of each 1024B row -> 16% write amp).
__global__ __launch_bounds__(256, 4) void tpw_gemm_kernel(
    const unsigned short* __restrict__ h3, const float* __restrict__ w4,
    __hip_bfloat16* __restrict__ tpw)
{
    __shared__ unsigned short uni[64 * 136];  // epi buffer only (17.4 KB)
    __shared__ unsigned short Bp[128 * 72];   // [n][k] pad 8 (18.4 KB)
    int l = blockIdx.y, t = threadIdx.x;
    int lane = t & 63, wid = t >> 6;
    unsigned short* tplane = (unsigned short*)tpw + (size_t)l * N_EDGE * C_DIM;

    for (int idx = t; idx < RAD_H * C_DIM; idx += 256) {
        int k = idx >> 7, n = idx & 127;
        Bp[n * 72 + k] = bf16bits(w4[k * (NL * C_DIM) + l * C_DIM + n] * R_SCALE);
    }
    __syncthreads();

    short8 bfr[2][8];
    #pragma unroll
    for (int s = 0; s < 2; ++s)
        #pragma unroll
        for (int f = 0; f < 8; ++f)
            bfr[s][f] = *(const short8*)&Bp[(f * 16 + (lane & 15)) * 72 + s * 32 + (lane >> 4) * 8];

    const int ntiles = (N_EDGE + TPW_ROWS - 1) / TPW_ROWS;   // 1563
    short8 a_cur[2];
    {
        int arow = min((int)blockIdx.x * TPW_ROWS + wid * 16 + (lane & 15), N_EDGE - 1);
        a_cur[0] = *(const short8*)&h3[(size_t)arow * RAD_H + 0 * 32 + (lane >> 4) * 8];
        a_cur[1] = *(const short8*)&h3[(size_t)arow * RAD_H + 1 * 32 + (lane >> 4) * 8];
    }
    for (int tile = blockIdx.x; tile < ntiles; tile += gridDim.x) {
        int i0 = tile * TPW_ROWS;
        short8 a_nxt[2];
        int ntile2 = tile + gridDim.x;
        if (ntile2 < ntiles) {
            int arow = min(ntile2 * TPW_ROWS + wid * 16 + (lane & 15), N_EDGE - 1);
            a_nxt[0] = *(const short8*)&h3[(size_t)arow * RAD_H + 0 * 32 + (lane >> 4) * 8];
            a_nxt[1] = *(const short8*)&h3[(size_t)arow * RAD_H + 1 * 32 + (lane >> 4) * 8];
        }

        f32x4 acc[8] = {};
        #pragma unroll
        for (int s = 0; s < 2; ++s)
            #pragma unroll
            for (int f = 0; f < 8; ++f)
                acc[f] = __builtin_amdgcn_mfma_f32_16x16x32_bf16(a_cur[s], bfr[s][f], acc[f], 0, 0, 0);

        __syncthreads();    // prev copy-out done before epi overwrite
        #pragma unroll
        for (int f = 0; f < 8; ++f)
            #pragma unroll
            for (int r = 0; r < 4; ++r)
                uni[(wid * 16 + (lane >> 4) * 4 + r) * 136 + f * 16 + (lane & 15)] = bf16bits(acc[f][r]);
        __syncthreads();    // epi ready

        {
            int row = t >> 2, q = t & 3;
            if (i0 + row < N_EDGE) {
                unsigned short* dst = tplane + (size_t)(i0 + row) * C_DIM + q * 32;
                #pragma unroll
                for (int v = 0; v < 4; ++v)
                    *(short8*)(dst + v * 8) = *(const short8*)&uni[row * 136 + q * 32 + v * 8];
            }
        }
        a_cur[0] = a_nxt[0];
        a_cur[1] = a_nxt[1];
    }
}

// ---------------- stream gather v7: l-major tpw planes ----------------
__global__ __launch_bounds__(256, 4) void stream_gather_kernel(
    const int* __restrict__ offs, const int* __restrict__ sid_arr,
    const float* __restrict__ x, const float* __restrict__ ea_perm,
    const __hip_bfloat16* __restrict__ tpw, unsigned short* __restrict__ msgbf)
{
    __shared__ float eas[128 * SH_DIM];   // 8 KB
    __shared__ int   sids[128];
    int n = blockIdx.x, t = threadIdx.x;
    int cq = t & 63, l = t >> 6;
    int c0 = cq * 2;
    const unsigned short* tplane = (const unsigned short*)tpw + (size_t)l * N_EDGE * C_DIM;
    float acc[7][2] = {};
    int nm = 2 * l + 1;
    int start = offs[n], end = offs[n + 1];

    for (int cs = start; cs < end; cs += 128) {
        int clen = min(128, end - cs);
        {
            const float4* src = (const float4*)(ea_perm + (size_t)cs * SH_DIM);
            float4* dst = (float4*)eas;
            for (int i = t; i < clen * 4; i += 256) dst[i] = src[i];
            for (int i = t; i < clen; i += 256) sids[i] = sid_arr[cs + i];
        }
        __syncthreads();

        for (int base = 0; base < clen; base += 8) {
            int idxb[8], sidb[8];
            #pragma unroll
            for (int j = 0; j < 8; ++j) idxb[j] = min(base + j, clen - 1);
            #pragma unroll
            for (int j = 0; j < 8; ++j) sidb[j] = sids[idxb[j]];

            unsigned int tpb[8];
            float2 xv[8];
            #pragma unroll
            for (int j = 0; j < 8; ++j)
                tpb[j] = *(const unsigned int*)(tplane + (size_t)(cs + idxb[j]) * C_DIM + c0);
            #pragma unroll
            for (int j = 0; j < 8; ++j)
                xv[j] = *(const float2*)(x + (size_t)sidb[j] * C_DIM + c0);
            asm volatile("" : "+v"(tpb[0]), "+v"(tpb[1]), "+v"(tpb[2]), "+v"(tpb[3]),
                              "+v"(tpb[4]), "+v"(tpb[5]), "+v"(tpb[6]), "+v"(tpb[7]),
                              "+v"(xv[0].x), "+v"(xv[0].y), "+v"(xv[1].x), "+v"(xv[1].y),
                              "+v"(xv[2].x), "+v"(xv[2].y), "+v"(xv[3].x), "+v"(xv[3].y),
                              "+v"(xv[4].x), "+v"(xv[4].y), "+v"(xv[5].x), "+v"(xv[5].y),
                              "+v"(xv[6].x), "+v"(xv[6].y), "+v"(xv[7].x), "+v"(xv[7].y));

            #pragma unroll
            for (int j = 0; j < 8; ++j) {
                unsigned int lo = (tpb[j] & 0xFFFFu) << 16;
                unsigned int hi = tpb[j] & 0xFFFF0000u;
                float tp0 = __uint_as_float(lo);
                float tp1 = __uint_as_float(hi);
                bool valid = (base + j < clen);
                float xt0 = valid ? tp0 * xv[j].x : 0.f;
                float xt1 = valid ? tp1 * xv[j].y : 0.f;
                const float* ear = eas + idxb[j] * SH_DIM + l * l;
                #pragma unroll
                for (int m = 0; m < 7; ++m)
                    if (m < nm) { acc[m][0] += ear[m] * xt0; acc[m][1] += ear[m] * xt1; }
            }
        }
        __syncthreads();
    }
    unsigned short* mout = msgbf + (size_t)n * (SH_DIM * C_DIM) + (size_t)(l * l) * C_DIM + c0;
    #pragma unroll
    for (int m = 0; m < 7; ++m)
        if (m < nm) *(unsigned int*)(mout + (size_t)m * C_DIM) = packbf2(acc[m][0], acc[m][1]);
}

// ---------------- fallback fused gather (h3 bf16, perm-ordered; msg bf16 out) ----------------
__global__ __launch_bounds__(512, 4) void fused_gather_kernel(
    const int* __restrict__ perm, const int* __restrict__ offs,
    const int* __restrict__ sender, const float* __restrict__ x,
    const float* __restrict__ edge_attrs, const unsigned short* __restrict__ h3,
    const float* __restrict__ w4, unsigned short* __restrict__ msgbf)
{
    int n = blockIdx.x, t = threadIdx.x;
    int c = t & 127, l = t >> 7;
    float wc[RAD_H];
    #pragma unroll
    for (int k = 0; k < RAD_H; ++k)
        wc[k] = w4[k * (NL * C_DIM) + l * C_DIM + c];

    float acc[7] = {0.f, 0.f, 0.f, 0.f, 0.f, 0.f, 0.f};
    int nm = 2 * l + 1;
    int start = offs[n], end = offs[n + 1];
    if (start < end) {
        int e = __builtin_amdgcn_readfirstlane(perm[start]);
        int s = __builtin_amdgcn_readfirstlane(sender[e]);
        for (int idx = start; idx < end; ++idx) {
            #pragma unroll
            for (int k = 0; k < RAD_H; k += 8)
                asm volatile("" : "+v"(wc[k]), "+v"(wc[k+1]), "+v"(wc[k+2]), "+v"(wc[k+3]),
                                  "+v"(wc[k+4]), "+v"(wc[k+5]), "+v"(wc[k+6]), "+v"(wc[k+7]));
            int e_cur = e, s_cur = s;
            if (idx + 1 < end) {
                e = __builtin_amdgcn_readfirstlane(perm[idx + 1]);
                s = __builtin_amdgcn_readfirstlane(sender[e]);
            }
            const unsigned short* h3r = h3 + (size_t)idx * RAD_H;   // perm-ordered bf16
            float xv = x[(size_t)s_cur * C_DIM + c];
            float tp0 = 0.f, tp1 = 0.f, tp2 = 0.f, tp3 = 0.f;
            #pragma unroll
            for (int q = 0; q < RAD_H / 4; ++q) {
                tp0 += bf16val(h3r[4 * q + 0]) * wc[4 * q + 0];
                tp1 += bf16val(h3r[4 * q + 1]) * wc[4 * q + 1];
                tp2 += bf16val(h3r[4 * q + 2]) * wc[4 * q + 2];
                tp3 += bf16val(h3r[4 * q + 3]) * wc[4 * q + 3];
            }
            float tp = (tp0 + tp1) + (tp2 + tp3);
            float xt = xv * (tp * R_SCALE);
            const float* ear = edge_attrs + (size_t)e_cur * SH_DIM + l * l;
            #pragma unroll
            for (int j = 0; j < 7; ++j)
                if (j < nm) acc[j] += ear[j] * xt;
        }
    }
    unsigned short* mout = msgbf + (size_t)n * (SH_DIM * C_DIM) + (size_t)(l * l) * C_DIM + c;
    #pragma unroll
    for (int j = 0; j < 7; ++j)
        if (j < nm) mout[(size_t)j * C_DIM] = bf16bits(acc[j]);
}

// ---------------- out transform via MFMA v3: bf16 msg staged through LDS ----------------
__global__ __launch_bounds__(256, 3) void out_mfma_kernel(
    const unsigned short* __restrict__ msgbf, float* __restrict__ out,
    const float* __restrict__ w_out)
{
    __shared__ unsigned short As[64 * 136];    // 17.4 KB
    __shared__ unsigned short Bp[128 * 136];   // 34.8 KB
    int l = blockIdx.y, t = threadIdx.x;
    int lane = t & 63, wid = t >> 6;
    const int cnt = 2 * l + 1, ms = l * l;
    const int M = N_NODES * cnt;
    const int ntile = (M + 63) >> 6;
    if (blockIdx.x >= ntile) return;

    for (int idx = t; idx < C_DIM * C_DIM; idx += 256) {
        int k = idx >> 7, n = idx & 127;
        Bp[n * 136 + k] = bf16bits(w_out[((size_t)l * C_DIM + k) * C_DIM + n] * OUT_SCALE);
    }
    __syncthreads();

    for (int tile = blockIdx.x; tile < ntile; tile += gridDim.x) {
        int i0 = tile << 6;
        {   // stage A rows: coalesced bf16 copy (4 threads x 64B per 256B row)
            int r = t >> 2, q = t & 3;
            int g = min(i0 + r, M - 1);
            int node = g / cnt, mm = ms + (g - node * cnt);
            const unsigned short* src = msgbf + ((size_t)node * SH_DIM + mm) * C_DIM + q * 32;
            *(short8*)&As[r * 136 + q * 32 + 0]  = *(const short8*)(src + 0);
            *(short8*)&As[r * 136 + q * 32 + 8]  = *(const short8*)(src + 8);
            *(short8*)&As[r * 136 + q * 32 + 16] = *(const short8*)(src + 16);
            *(short8*)&As[r * 136 + q * 32 + 24] = *(const short8*)(src + 24);
        }
        __syncthreads();

        f32x4 acc[8] = {};
        #pragma unroll
        for (int ks = 0; ks < 4; ++ks) {
            short8 a = *(const short8*)&As[(wid * 16 + (lane & 15)) * 136 + ks * 32 + (lane >> 4) * 8];
            #pragma unroll
            for (int f = 0; f < 8; ++f) {
                short8 b = *(const short8*)&Bp[(f * 16 + (lane & 15)) * 136 + ks * 32 + (lane >> 4) * 8];
                acc[f] = __builtin_amdgcn_mfma_f32_16x16x32_bf16(a, b, acc[f], 0, 0, 0);
            }
        }
        __syncthreads();    // all A reads done before next iter's staging

        #pragma unroll
        for (int r = 0; r < 4; ++r) {
            int g = i0 + wid * 16 + (lane >> 4) * 4 + r;
            if (g < M) {
                int node = g / cnt, mm = ms + (g - node * cnt);
                float* dst = out + ((size_t)node * SH_DIM + mm) * C_DIM + (lane & 15);
                #pragma unroll
                for (int f = 0; f < 8; ++f)
                    dst[f * 16] = acc[f][r];
            }
        }
    }
}

extern "C" void kernel_launch(void* const* d_in, const int* in_sizes, int n_in,
                              void* d_out, int out_size, void* d_ws, size_t ws_size,
                              hipStream_t stream)
{
    const float* node_attrs = (const float*)d_in[0];
    const float* node_feats = (const float*)d_in[1];
    const float* edge_attrs = (const float*)d_in[2];
    const float* edge_feats = (const float*)d_in[3];
    const int*   edge_index = (const int*)d_in[4];
    const float* w_up   = (const float*)d_in[5];
    const float* w_rad1 = (const float*)d_in[6];
    const float* w_rad2 = (const float*)d_in[7];
    const float* w_rad3 = (const float*)d_in[8];
    const float* w_rad4 = (const float*)d_in[9];
    const float* w_skip = (const float*)d_in[10];
    const float* w_out  = (const float*)d_in[11];
    const int* sender = edge_index;
    const int* recv   = edge_index + N_EDGE;

    float* out = (float*)d_out;
    float* sc  = out + (size_t)N_NODES * SH_DIM * C_DIM;

    // workspace layout (~147 MB; ws >= 233.4 MB proven)
    float* x   = (float*)d_ws;
    unsigned short* h3 = (unsigned short*)(x + (size_t)N_NODES * C_DIM);  // bf16, perm-ordered
    int* deg    = (int*)(h3 + (size_t)N_EDGE * RAD_H);
    int* cursor = deg + 5120;
    int* offs   = cursor + 5120;
    int* perm   = offs + 5124;
    int* pos_of = perm + N_EDGE;
    __hip_bfloat16* tpw = (__hip_bfloat16*)(pos_of + N_EDGE);   // l-major planes
    int* sid_arr = (int*)(tpw + (size_t)N_EDGE * NL * C_DIM);
    float* ea_perm = (float*)(sid_arr + N_EDGE);
    unsigned short* msgbf = (unsigned short*)(ea_perm + (size_t)N_EDGE * SH_DIM);  // 20.5 MB
    size_t need = (size_t)((char*)(msgbf + (size_t)N_NODES * SH_DIM * C_DIM) - (char*)d_ws);
    int mode = (ws_size >= need) ? 1 : 0;

    hipMemsetAsync(deg, 0, 2 * 5120 * sizeof(int), stream);

    node_kernel<<<N_NODES, 128, 0, stream>>>(node_attrs, node_feats, w_skip, w_up, x, sc);

    // CSR build BEFORE radial (radial writes h3 in perm order via pos_of)
    hist_kernel<<<(N_EDGE + 255) / 256, 256, 0, stream>>>(recv, deg);
    scan_kernel<<<1, 256, 0, stream>>>(deg, offs);
    scatter_kernel<<<(N_EDGE + 255) / 256, 256, 0, stream>>>(recv, offs, cursor, perm, pos_of);

    radial_mfma_kernel<<<1563, 256, 0, stream>>>(edge_feats, pos_of, w_rad1, w_rad2, w_rad3, h3);

    if (mode == 1) {
        reorder_kernel<<<(N_EDGE + 255) / 256, 256, 0, stream>>>(perm, sender, edge_attrs, sid_arr, (float4*)ea_perm);
        tpw_gemm_kernel<<<dim3(391, 4), 256, 0, stream>>>(h3, w_rad4, tpw);
        stream_gather_kernel<<<N_NODES, 256, 0, stream>>>(offs, sid_arr, x, ea_perm, tpw, msgbf);
        out_mfma_kernel<<<dim3(547, 4), 256, 0, stream>>>(msgbf, out, w_out);
    } else {
        unsigned short* msgbf_fb = (unsigned short*)tpw;
        fused_gather_kernel<<<N_NODES, 512, 0, stream>>>(perm, offs, sender, x, edge_attrs, h3, w_rad4, msgbf_fb);
        out_mfma_kernel<<<dim3(547, 4), 256, 0, stream>>>(msgbf_fb, out, w_out);
    }
}